// Round 2
// baseline (855.290 us; speedup 1.0000x reference)
//
#include <hip/hip_runtime.h>
#include <math.h>

#define N_NODES 50000
#define N_EDGES 400000
#define E_TOT   450000   // + self loops
#define IN_DIM  133
#define HID     256
#define NEG_SLOPE 0.2f

// ---------------- wave helpers (wave64) ----------------
__device__ __forceinline__ float wave_max(float v) {
#pragma unroll
  for (int m = 1; m < 64; m <<= 1) v = fmaxf(v, __shfl_xor(v, m));
  return v;
}
__device__ __forceinline__ float wave_sum(float v) {
#pragma unroll
  for (int m = 1; m < 64; m <<= 1) v += __shfl_xor(v, m);
  return v;
}

// ---------------- CSR build ----------------
__global__ void zero_k(int* __restrict__ cnt, float* __restrict__ csum) {
  int t = blockIdx.x * 256 + threadIdx.x;
  if (t < N_NODES) cnt[t] = 0;
  if (t < 256) csum[t] = 0.f;
}

__global__ void hist_k(const int* __restrict__ ei, int* __restrict__ cnt) {
  int e = blockIdx.x * 256 + threadIdx.x;
  if (e >= E_TOT) return;
  int dst = (e < N_EDGES) ? ei[N_EDGES + e] : (e - N_EDGES);
  atomicAdd(&cnt[dst], 1);
}

__global__ __launch_bounds__(1024) void scan_k(const int* __restrict__ cnt,
                                               int* __restrict__ offs,
                                               int* __restrict__ pos) {
  __shared__ int bs[1024];
  const int t = threadIdx.x;
  const int CHUNK = 49;  // 1024*49 = 50176 >= 50000
  const int base = t * CHUNK;
  int s = 0;
  for (int i = 0; i < CHUNK; ++i) {
    int idx = base + i;
    if (idx < N_NODES) s += cnt[idx];
  }
  bs[t] = s;
  __syncthreads();
  for (int off = 1; off < 1024; off <<= 1) {
    int v = 0;
    if (t >= off) v = bs[t - off];
    __syncthreads();
    if (t >= off) bs[t] += v;
    __syncthreads();
  }
  int run = (t > 0) ? bs[t - 1] : 0;
  for (int i = 0; i < CHUNK; ++i) {
    int idx = base + i;
    if (idx < N_NODES) {
      offs[idx] = run;
      pos[idx] = run;
      run += cnt[idx];
    }
  }
  if (t == 1023) offs[N_NODES] = bs[1023];
}

__global__ void scatter_k(const int* __restrict__ ei, int* __restrict__ pos,
                          int* __restrict__ csr_src) {
  int e = blockIdx.x * 256 + threadIdx.x;
  if (e >= E_TOT) return;
  int src, dst;
  if (e < N_EDGES) { src = ei[e]; dst = ei[N_EDGES + e]; }
  else             { src = e - N_EDGES; dst = src; }
  int p = atomicAdd(&pos[dst], 1);
  csr_src[p] = src;
}

// ---------------- fp32 tiled GEMM (no fp32 MFMA on CDNA4 -> vector ALU) ----
#define BM 128
#define BN 128
#define BK 8

__global__ __launch_bounds__(256) void gemm_f32(
    const float* __restrict__ A, const float* __restrict__ B,
    float* __restrict__ C, int M, int N, int K) {
  __shared__ float As[BK][BM + 4];
  __shared__ float Bs[BK][BN + 4];
  const int bm = blockIdx.y * BM;
  const int bn = blockIdx.x * BN;
  const int tid = threadIdx.x;
  const int tx = tid & 15;   // 16 cols of micro-tiles
  const int ty = tid >> 4;   // 16 rows of micro-tiles
  float acc[8][8] = {};

  for (int k0 = 0; k0 < K; k0 += BK) {
    // stage A: 128 rows x 8 k   (scalar loads: A rows not 16B aligned for K=133)
#pragma unroll
    for (int i = 0; i < 4; ++i) {
      int f = tid + i * 256;
      int r = f >> 3, kk = f & 7;
      int row = bm + r, k = k0 + kk;
      As[kk][r] = (row < M && k < K) ? A[(size_t)row * K + k] : 0.f;
    }
    // stage B: 8 k x 128 cols, float4 (N multiple of 128, rows aligned)
    {
      int kk = tid >> 5, c = (tid & 31) * 4;
      int k = k0 + kk;
      float4 v = make_float4(0.f, 0.f, 0.f, 0.f);
      if (k < K) v = *(const float4*)(B + (size_t)k * N + bn + c);
      Bs[kk][c] = v.x; Bs[kk][c + 1] = v.y; Bs[kk][c + 2] = v.z; Bs[kk][c + 3] = v.w;
    }
    __syncthreads();
#pragma unroll
    for (int kk = 0; kk < BK; ++kk) {
      float a[8], b[8];
#pragma unroll
      for (int i = 0; i < 8; ++i) a[i] = As[kk][ty * 8 + i];
#pragma unroll
      for (int j = 0; j < 8; ++j) b[j] = Bs[kk][tx * 8 + j];
#pragma unroll
      for (int i = 0; i < 8; ++i)
#pragma unroll
        for (int j = 0; j < 8; ++j) acc[i][j] = fmaf(a[i], b[j], acc[i][j]);
    }
    __syncthreads();
  }
#pragma unroll
  for (int i = 0; i < 8; ++i) {
    int row = bm + ty * 8 + i;
    if (row < M) {
      float* cp = C + (size_t)row * N + bn + tx * 8;
      *(float4*)cp = make_float4(acc[i][0], acc[i][1], acc[i][2], acc[i][3]);
      *(float4*)(cp + 4) = make_float4(acc[i][4], acc[i][5], acc[i][6], acc[i][7]);
    }
  }
}

// ---------------- per-node attention logits: a_s/a_d = <xp[n,h,:], att[h,:]> -
template <int HEADS>
__global__ __launch_bounds__(256) void att_logits(
    const float* __restrict__ xp, const float* __restrict__ att_src,
    const float* __restrict__ att_dst, float* __restrict__ a_s,
    float* __restrict__ a_d) {
  const int wid = (blockIdx.x << 2) + (threadIdx.x >> 6);  // one wave per (n,h)
  const int lane = threadIdx.x & 63;
  if (wid >= N_NODES * HEADS) return;
  const int head = wid % HEADS;
  const float4 xv = *(const float4*)(xp + (size_t)wid * HID + lane * 4);
  const float4 sv = *(const float4*)(att_src + head * HID + lane * 4);
  const float4 dv = *(const float4*)(att_dst + head * HID + lane * 4);
  float ps = xv.x * sv.x + xv.y * sv.y + xv.z * sv.z + xv.w * sv.w;
  float pd = xv.x * dv.x + xv.y * dv.y + xv.z * dv.z + xv.w * dv.w;
  ps = wave_sum(ps);
  pd = wave_sum(pd);
  if (lane == 0) { a_s[wid] = ps; a_d[wid] = pd; }
}

// ---------------- fused segment softmax + weighted gather-aggregate + bias + ELU
template <int HEADS>
__global__ __launch_bounds__(256) void gat_agg(
    const float* __restrict__ xp, const float* __restrict__ a_s,
    const float* __restrict__ a_d, const int* __restrict__ offs,
    const int* __restrict__ csr_src, const float* __restrict__ bias,
    float* __restrict__ out) {
  const int wid = (blockIdx.x << 2) + (threadIdx.x >> 6);  // one wave per (n,h)
  const int lane = threadIdx.x & 63;
  if (wid >= N_NODES * HEADS) return;
  const int node = wid / HEADS;
  const int head = wid % HEADS;
  const int beg = offs[node], end = offs[node + 1];
  const float adt = a_d[wid];

  // pass 1: segment max (lane-parallel over edges)
  float m = -INFINITY;
  for (int i = beg + lane; i < end; i += 64) {
    int s = csr_src[i];
    float e = a_s[s * HEADS + head] + adt;
    e = e > 0.f ? e : NEG_SLOPE * e;
    m = fmaxf(m, e);
  }
  m = wave_max(m);

  // pass 2: segment sum of exp
  float z = 0.f;
  for (int i = beg + lane; i < end; i += 64) {
    int s = csr_src[i];
    float e = a_s[s * HEADS + head] + adt;
    e = e > 0.f ? e : NEG_SLOPE * e;
    z += __expf(e - m);
  }
  z = wave_sum(z) + 1e-16f;
  const float inv_z = 1.f / z;

  // pass 3: serial edges, lanes parallel over 256 channels (float4 each)
  const int col = lane * 4;
  float4 acc = make_float4(0.f, 0.f, 0.f, 0.f);
  for (int i = beg; i < end; ++i) {
    int s = csr_src[i];
    float e = a_s[s * HEADS + head] + adt;
    e = e > 0.f ? e : NEG_SLOPE * e;
    float alpha = __expf(e - m) * inv_z;
    const float4 v = *(const float4*)(xp + ((size_t)(s * HEADS + head)) * HID + col);
    acc.x = fmaf(alpha, v.x, acc.x);
    acc.y = fmaf(alpha, v.y, acc.y);
    acc.z = fmaf(alpha, v.z, acc.z);
    acc.w = fmaf(alpha, v.w, acc.w);
  }

  const int oc = head * HID + col;
  const float4 bb = *(const float4*)(bias + oc);
  float o0 = acc.x + bb.x, o1 = acc.y + bb.y, o2 = acc.z + bb.z, o3 = acc.w + bb.w;
  o0 = o0 > 0.f ? o0 : __expf(o0) - 1.f;   // ELU (alpha=1)
  o1 = o1 > 0.f ? o1 : __expf(o1) - 1.f;
  o2 = o2 > 0.f ? o2 : __expf(o2) - 1.f;
  o3 = o3 > 0.f ? o3 : __expf(o3) - 1.f;
  *(float4*)(out + (size_t)node * (HEADS * HID) + oc) = make_float4(o0, o1, o2, o3);
}

// ---------------- mean over nodes + fc head ----------------
__global__ void colsum_k(const float* __restrict__ h2, float* __restrict__ sum) {
  const int c = threadIdx.x;           // 256 cols
  const int r0 = blockIdx.x * 250;     // 200 blocks * 250 rows = 50000
  float s = 0.f;
  for (int r = r0; r < r0 + 250; ++r) s += h2[(size_t)r * HID + c];
  atomicAdd(&sum[c], s);
}

__global__ void final_k(const float* __restrict__ csum, const float* __restrict__ fcW,
                        const float* __restrict__ fcb, float* __restrict__ out) {
  const int lane = threadIdx.x;  // 64 threads
  float p0 = 0.f, p1 = 0.f, p2 = 0.f;
  for (int c = lane; c < HID; c += 64) {
    float v = csum[c] * (1.f / (float)N_NODES);
    p0 = fmaf(v, fcW[c * 3 + 0], p0);
    p1 = fmaf(v, fcW[c * 3 + 1], p1);
    p2 = fmaf(v, fcW[c * 3 + 2], p2);
  }
  p0 = wave_sum(p0); p1 = wave_sum(p1); p2 = wave_sum(p2);
  if (lane == 0) {
    out[0] = p0 + fcb[0];
    out[1] = p1 + fcb[1];
    out[2] = p2 + fcb[2];
  }
}

// ---------------- launch ----------------
extern "C" void kernel_launch(void* const* d_in, const int* in_sizes, int n_in,
                              void* d_out, int out_size, void* d_ws, size_t ws_size,
                              hipStream_t stream) {
  const float* x   = (const float*)d_in[0];
  const int*   ei  = (const int*)d_in[1];
  const float* W1  = (const float*)d_in[2];
  const float* as1 = (const float*)d_in[3];
  const float* ad1 = (const float*)d_in[4];
  const float* b1  = (const float*)d_in[5];
  const float* W2  = (const float*)d_in[6];
  const float* as2 = (const float*)d_in[7];
  const float* ad2 = (const float*)d_in[8];
  const float* b2  = (const float*)d_in[9];
  const float* fcW = (const float*)d_in[10];
  const float* fcb = (const float*)d_in[11];
  float* out = (float*)d_out;

  char* w = (char*)d_ws;
  size_t o = 0;
  auto alloc = [&](size_t bytes) {
    void* p = w + o;
    o = (o + bytes + 255) & ~(size_t)255;
    return p;
  };
  float* XP  = (float*)alloc((size_t)N_NODES * 512 * 4);  // xp layer1 / xp layer2
  float* H   = (float*)alloc((size_t)N_NODES * 512 * 4);  // h1 / h2
  float* aS1 = (float*)alloc((size_t)N_NODES * 2 * 4);
  float* aD1 = (float*)alloc((size_t)N_NODES * 2 * 4);
  float* aS2 = (float*)alloc((size_t)N_NODES * 4);
  float* aD2 = (float*)alloc((size_t)N_NODES * 4);
  int* cnt   = (int*)alloc((size_t)N_NODES * 4);
  int* offs  = (int*)alloc((size_t)(N_NODES + 1) * 4);
  int* pos   = (int*)alloc((size_t)(N_NODES + 1) * 4);
  int* csr   = (int*)alloc((size_t)E_TOT * 4);
  float* csum = (float*)alloc(256 * 4);

  // CSR build (shared by both layers)
  zero_k<<<(N_NODES + 255) / 256, 256, 0, stream>>>(cnt, csum);
  hist_k<<<(E_TOT + 255) / 256, 256, 0, stream>>>(ei, cnt);
  scan_k<<<1, 1024, 0, stream>>>(cnt, offs, pos);
  scatter_k<<<(E_TOT + 255) / 256, 256, 0, stream>>>(ei, pos, csr);

  // layer 1: x[50000,133] @ W1[133,512] -> XP ; logits ; aggregate -> H (elu'd)
  gemm_f32<<<dim3(512 / BN, (N_NODES + BM - 1) / BM), 256, 0, stream>>>(
      x, W1, XP, N_NODES, 512, IN_DIM);
  att_logits<2><<<(N_NODES * 2 + 3) / 4, 256, 0, stream>>>(XP, as1, ad1, aS1, aD1);
  gat_agg<2><<<(N_NODES * 2 + 3) / 4, 256, 0, stream>>>(XP, aS1, aD1, offs, csr, b1, H);

  // layer 2: H[50000,512] @ W2[512,256] -> XP ; logits ; aggregate -> H (elu'd)
  gemm_f32<<<dim3(256 / BN, (N_NODES + BM - 1) / BM), 256, 0, stream>>>(
      H, W2, XP, N_NODES, 256, 512);
  att_logits<1><<<(N_NODES + 3) / 4, 256, 0, stream>>>(XP, as2, ad2, aS2, aD2);
  gat_agg<1><<<(N_NODES + 3) / 4, 256, 0, stream>>>(XP, aS2, aD2, offs, csr, b2, H);

  // mean over nodes + fc
  colsum_k<<<200, 256, 0, stream>>>(H, csum);
  final_k<<<1, 64, 0, stream>>>(csum, fcW, fcb, out);
}

// Round 5
// 803.190 us; speedup vs baseline: 1.0649x; 1.0649x over previous
//
#include <hip/hip_runtime.h>
#include <math.h>

#define N_NODES 50000
#define N_EDGES 400000
#define E_TOT   450000   // + self loops
#define IN_DIM  133
#define HID     256
#define NEG_SLOPE 0.2f

typedef unsigned int uint;

// ---------------- bf16 helpers ----------------
__device__ __forceinline__ float bf_lo(uint u) { return __uint_as_float(u << 16); }
__device__ __forceinline__ float bf_hi(uint u) { return __uint_as_float(u & 0xffff0000u); }
__device__ __forceinline__ uint f2bf1(float f) {  // round-to-nearest-even
  uint u = __float_as_uint(f);
  return (u + 0x7fffu + ((u >> 16) & 1u)) >> 16;
}
__device__ __forceinline__ uint pack_bf2(float lo, float hi) {
  return f2bf1(lo) | (f2bf1(hi) << 16);
}

// ---------------- wave helpers (wave64) ----------------
__device__ __forceinline__ float wave_max(float v) {
#pragma unroll
  for (int m = 1; m < 64; m <<= 1) v = fmaxf(v, __shfl_xor(v, m));
  return v;
}
__device__ __forceinline__ float wave_sum(float v) {
#pragma unroll
  for (int m = 1; m < 64; m <<= 1) v += __shfl_xor(v, m);
  return v;
}

// ---------------- CSR build ----------------
__global__ void zero_k(int* __restrict__ cnt, float* __restrict__ csum) {
  int t = blockIdx.x * 256 + threadIdx.x;
  if (t < N_NODES) cnt[t] = 0;
  if (t < 256) csum[t] = 0.f;
}

__global__ void hist_k(const int* __restrict__ ei, int* __restrict__ cnt) {
  int e = blockIdx.x * 256 + threadIdx.x;
  if (e >= E_TOT) return;
  int dst = (e < N_EDGES) ? ei[N_EDGES + e] : (e - N_EDGES);
  atomicAdd(&cnt[dst], 1);
}

__global__ __launch_bounds__(1024) void scan_k(const int* __restrict__ cnt,
                                               int* __restrict__ offs,
                                               int* __restrict__ pos) {
  __shared__ int bs[1024];
  const int t = threadIdx.x;
  const int CHUNK = 49;  // 1024*49 = 50176 >= 50000
  const int base = t * CHUNK;
  int s = 0;
  for (int i = 0; i < CHUNK; ++i) {
    int idx = base + i;
    if (idx < N_NODES) s += cnt[idx];
  }
  bs[t] = s;
  __syncthreads();
  for (int off = 1; off < 1024; off <<= 1) {
    int v = 0;
    if (t >= off) v = bs[t - off];
    __syncthreads();
    if (t >= off) bs[t] += v;
    __syncthreads();
  }
  int run = (t > 0) ? bs[t - 1] : 0;
  for (int i = 0; i < CHUNK; ++i) {
    int idx = base + i;
    if (idx < N_NODES) {
      offs[idx] = run;
      pos[idx] = run;
      run += cnt[idx];
    }
  }
  if (t == 1023) offs[N_NODES] = bs[1023];
}

__global__ void scatter_k(const int* __restrict__ ei, int* __restrict__ pos,
                          int* __restrict__ csr_src) {
  int e = blockIdx.x * 256 + threadIdx.x;
  if (e >= E_TOT) return;
  int src, dst;
  if (e < N_EDGES) { src = ei[e]; dst = ei[N_EDGES + e]; }
  else             { src = e - N_EDGES; dst = src; }
  int p = atomicAdd(&pos[dst], 1);
  csr_src[p] = src;
}

// ---------------- fp32 GEMM, bf16 output (no fp32 MFMA on CDNA4) ----------
// micro-tile cols {bn+tx*4+j, bn+64+tx*4+j}: float4 LDS reads, <=2-way bank alias
__global__ __launch_bounds__(256) void gemm_bf16out(
    const float* __restrict__ A, const float* __restrict__ B,
    unsigned short* __restrict__ C, int M, int N, int K) {
  __shared__ float As[8][132];
  __shared__ float Bs[8][132];
  const int bm = blockIdx.y * 128;
  const int bn = blockIdx.x * 128;
  const int tid = threadIdx.x;
  const int tx = tid & 15;
  const int ty = tid >> 4;
  float acc[8][8] = {};

  for (int k0 = 0; k0 < K; k0 += 8) {
    // stage A: 128 rows x 8 k (scalar: K=133 rows unaligned)
#pragma unroll
    for (int i = 0; i < 4; ++i) {
      int f = tid + i * 256;
      int r = f >> 3, kk = f & 7;
      int row = bm + r, k = k0 + kk;
      As[kk][r] = (row < M && k < K) ? A[(size_t)row * K + k] : 0.f;
    }
    // stage B: 8 k x 128 cols, float4 both sides
    {
      int kk = tid >> 5, c = (tid & 31) * 4;
      int k = k0 + kk;
      float4 v = make_float4(0.f, 0.f, 0.f, 0.f);
      if (k < K) v = *(const float4*)(B + (size_t)k * N + bn + c);
      *(float4*)&Bs[kk][c] = v;
    }
    __syncthreads();
#pragma unroll
    for (int kk = 0; kk < 8; ++kk) {
      float a[8], b[8];
      *(float4*)&a[0] = *(const float4*)&As[kk][ty * 8];
      *(float4*)&a[4] = *(const float4*)&As[kk][ty * 8 + 4];
      *(float4*)&b[0] = *(const float4*)&Bs[kk][tx * 4];
      *(float4*)&b[4] = *(const float4*)&Bs[kk][64 + tx * 4];
#pragma unroll
      for (int i = 0; i < 8; ++i)
#pragma unroll
        for (int j = 0; j < 8; ++j) acc[i][j] = fmaf(a[i], b[j], acc[i][j]);
    }
    __syncthreads();
  }
#pragma unroll
  for (int i = 0; i < 8; ++i) {
    int row = bm + ty * 8 + i;
    if (row < M) {
      unsigned short* cp = C + (size_t)row * N;
      uint2 w0 = make_uint2(pack_bf2(acc[i][0], acc[i][1]), pack_bf2(acc[i][2], acc[i][3]));
      uint2 w1 = make_uint2(pack_bf2(acc[i][4], acc[i][5]), pack_bf2(acc[i][6], acc[i][7]));
      *(uint2*)(cp + bn + tx * 4) = w0;
      *(uint2*)(cp + bn + 64 + tx * 4) = w1;
    }
  }
}

// ---------------- per-(node,head) attention logits from bf16 xp ------------
template <int HEADS>
__global__ __launch_bounds__(256) void att_logits(
    const unsigned short* __restrict__ xpb, const float* __restrict__ att_src,
    const float* __restrict__ att_dst, float* __restrict__ a_s,
    float* __restrict__ a_d) {
  const int wid = (blockIdx.x << 2) + (threadIdx.x >> 6);  // one wave per (n,h)
  const int lane = threadIdx.x & 63;
  if (wid >= N_NODES * HEADS) return;
  const int head = wid % HEADS;
  const uint2 xv = *(const uint2*)(xpb + (size_t)wid * HID + lane * 4);
  const float x0 = bf_lo(xv.x), x1 = bf_hi(xv.x), x2 = bf_lo(xv.y), x3 = bf_hi(xv.y);
  const float4 sv = *(const float4*)(att_src + head * HID + lane * 4);
  const float4 dv = *(const float4*)(att_dst + head * HID + lane * 4);
  float ps = x0 * sv.x + x1 * sv.y + x2 * sv.z + x3 * sv.w;
  float pd = x0 * dv.x + x1 * dv.y + x2 * dv.z + x3 * dv.w;
  ps = wave_sum(ps);
  pd = wave_sum(pd);
  if (lane == 0) { a_s[wid] = ps; a_d[wid] = pd; }
}

// ---------- fused segment softmax + bf16 gather-aggregate + bias + ELU -----
// one wave per NODE (all heads). deg<=64 fast path: logits computed once,
// alpha held per-lane, pulled by __shfl in the accumulate pass.
template <int HEADS>
__global__ __launch_bounds__(256) void gat_agg(
    const unsigned short* __restrict__ xpb, const float* __restrict__ a_s,
    const float* __restrict__ a_d, const int* __restrict__ offs,
    const int* __restrict__ csr, const float* __restrict__ bias,
    float* __restrict__ out) {
  const int node = (blockIdx.x << 2) + (threadIdx.x >> 6);
  const int lane = threadIdx.x & 63;
  if (node >= N_NODES) return;
  const int beg = offs[node], end = offs[node + 1];
  const int deg = end - beg;
  const float ad0 = a_d[node * HEADS + 0];
  const float ad1 = (HEADS == 2) ? a_d[node * HEADS + 1] : 0.f;

  if (deg <= 64) {
    int s = 0;
    float e0 = -INFINITY, e1 = -INFINITY;
    if (lane < deg) {
      s = csr[beg + lane];
      float v0 = a_s[s * HEADS + 0] + ad0;
      e0 = v0 > 0.f ? v0 : NEG_SLOPE * v0;
      if (HEADS == 2) {
        float v1 = a_s[s * HEADS + 1] + ad1;
        e1 = v1 > 0.f ? v1 : NEG_SLOPE * v1;
      }
    }
    const float m0 = wave_max(e0);
    const float p0 = (lane < deg) ? __expf(e0 - m0) : 0.f;
    const float z0 = wave_sum(p0);
    const float al0 = p0 / (z0 + 1e-16f);
    float al1 = 0.f;
    if (HEADS == 2) {
      const float m1 = wave_max(e1);
      const float p1 = (lane < deg) ? __expf(e1 - m1) : 0.f;
      const float z1 = wave_sum(p1);
      al1 = p1 / (z1 + 1e-16f);
    }

    if (HEADS == 2) {
      float acc[8] = {};
      for (int i = 0; i < deg; ++i) {
        int si = __shfl(s, i);
        float a0 = __shfl(al0, i);
        float a1 = __shfl(al1, i);
        float aa = (lane < 32) ? a0 : a1;   // lanes 0-31: head0, 32-63: head1
        uint4 v = *(const uint4*)(xpb + (size_t)si * 512 + lane * 8);
        acc[0] = fmaf(aa, bf_lo(v.x), acc[0]);
        acc[1] = fmaf(aa, bf_hi(v.x), acc[1]);
        acc[2] = fmaf(aa, bf_lo(v.y), acc[2]);
        acc[3] = fmaf(aa, bf_hi(v.y), acc[3]);
        acc[4] = fmaf(aa, bf_lo(v.z), acc[4]);
        acc[5] = fmaf(aa, bf_hi(v.z), acc[5]);
        acc[6] = fmaf(aa, bf_lo(v.w), acc[6]);
        acc[7] = fmaf(aa, bf_hi(v.w), acc[7]);
      }
      const int col = lane * 8;  // global col in [0,512)
      const float4 b0 = *(const float4*)(bias + col);
      const float4 b1 = *(const float4*)(bias + col + 4);
      float o[8];
      o[0] = acc[0] + b0.x; o[1] = acc[1] + b0.y; o[2] = acc[2] + b0.z; o[3] = acc[3] + b0.w;
      o[4] = acc[4] + b1.x; o[5] = acc[5] + b1.y; o[6] = acc[6] + b1.z; o[7] = acc[7] + b1.w;
#pragma unroll
      for (int j = 0; j < 8; ++j) o[j] = o[j] > 0.f ? o[j] : __expf(o[j]) - 1.f;
      float* op = out + (size_t)node * 512 + col;
      *(float4*)op = make_float4(o[0], o[1], o[2], o[3]);
      *(float4*)(op + 4) = make_float4(o[4], o[5], o[6], o[7]);
    } else {
      float acc[4] = {};
      for (int i = 0; i < deg; ++i) {
        int si = __shfl(s, i);
        float aa = __shfl(al0, i);
        uint2 v = *(const uint2*)(xpb + (size_t)si * 256 + lane * 4);
        acc[0] = fmaf(aa, bf_lo(v.x), acc[0]);
        acc[1] = fmaf(aa, bf_hi(v.x), acc[1]);
        acc[2] = fmaf(aa, bf_lo(v.y), acc[2]);
        acc[3] = fmaf(aa, bf_hi(v.y), acc[3]);
      }
      const int col = lane * 4;
      const float4 bb = *(const float4*)(bias + col);
      float o0 = acc[0] + bb.x, o1 = acc[1] + bb.y, o2 = acc[2] + bb.z, o3 = acc[3] + bb.w;
      o0 = o0 > 0.f ? o0 : __expf(o0) - 1.f;
      o1 = o1 > 0.f ? o1 : __expf(o1) - 1.f;
      o2 = o2 > 0.f ? o2 : __expf(o2) - 1.f;
      o3 = o3 > 0.f ? o3 : __expf(o3) - 1.f;
      *(float4*)(out + (size_t)node * 256 + col) = make_float4(o0, o1, o2, o3);
    }
  } else {
    // rare fallback (deg > 64): 3-pass per head, bf16 gathers
    for (int h = 0; h < HEADS; ++h) {
      const float adh = (h == 0) ? ad0 : ad1;
      float m = -INFINITY;
      for (int i = beg + lane; i < end; i += 64) {
        int s2 = csr[i];
        float e = a_s[s2 * HEADS + h] + adh;
        e = e > 0.f ? e : NEG_SLOPE * e;
        m = fmaxf(m, e);
      }
      m = wave_max(m);
      float z = 0.f;
      for (int i = beg + lane; i < end; i += 64) {
        int s2 = csr[i];
        float e = a_s[s2 * HEADS + h] + adh;
        e = e > 0.f ? e : NEG_SLOPE * e;
        z += __expf(e - m);
      }
      z = wave_sum(z) + 1e-16f;
      const float invz = 1.f / z;
      float acc[4] = {};
      for (int i = beg; i < end; ++i) {
        int s2 = csr[i];
        float e = a_s[s2 * HEADS + h] + adh;
        e = e > 0.f ? e : NEG_SLOPE * e;
        float al = __expf(e - m) * invz;
        uint2 v = *(const uint2*)(xpb + ((size_t)s2 * HEADS + h) * HID + lane * 4);
        acc[0] = fmaf(al, bf_lo(v.x), acc[0]);
        acc[1] = fmaf(al, bf_hi(v.x), acc[1]);
        acc[2] = fmaf(al, bf_lo(v.y), acc[2]);
        acc[3] = fmaf(al, bf_hi(v.y), acc[3]);
      }
      const int oc = h * HID + lane * 4;
      const float4 bb = *(const float4*)(bias + oc);
      float o0 = acc[0] + bb.x, o1 = acc[1] + bb.y, o2 = acc[2] + bb.z, o3 = acc[3] + bb.w;
      o0 = o0 > 0.f ? o0 : __expf(o0) - 1.f;
      o1 = o1 > 0.f ? o1 : __expf(o1) - 1.f;
      o2 = o2 > 0.f ? o2 : __expf(o2) - 1.f;
      o3 = o3 > 0.f ? o3 : __expf(o3) - 1.f;
      *(float4*)(out + (size_t)node * (HEADS * HID) + oc) = make_float4(o0, o1, o2, o3);
    }
  }
}

// ---------------- mean over nodes + fc head ----------------
__global__ void colsum_k(const float* __restrict__ h2, float* __restrict__ sum) {
  const int c = threadIdx.x;           // 256 cols
  const int r0 = blockIdx.x * 250;     // 200 blocks * 250 rows = 50000
  float s = 0.f;
  for (int r = r0; r < r0 + 250; ++r) s += h2[(size_t)r * HID + c];
  atomicAdd(&sum[c], s);
}

__global__ void final_k(const float* __restrict__ csum, const float* __restrict__ fcW,
                        const float* __restrict__ fcb, float* __restrict__ out) {
  const int lane = threadIdx.x;  // 64 threads
  float p0 = 0.f, p1 = 0.f, p2 = 0.f;
  for (int c = lane; c < HID; c += 64) {
    float v = csum[c] * (1.f / (float)N_NODES);
    p0 = fmaf(v, fcW[c * 3 + 0], p0);
    p1 = fmaf(v, fcW[c * 3 + 1], p1);
    p2 = fmaf(v, fcW[c * 3 + 2], p2);
  }
  p0 = wave_sum(p0); p1 = wave_sum(p1); p2 = wave_sum(p2);
  if (lane == 0) {
    out[0] = p0 + fcb[0];
    out[1] = p1 + fcb[1];
    out[2] = p2 + fcb[2];
  }
}

// ---------------- launch ----------------
extern "C" void kernel_launch(void* const* d_in, const int* in_sizes, int n_in,
                              void* d_out, int out_size, void* d_ws, size_t ws_size,
                              hipStream_t stream) {
  const float* x   = (const float*)d_in[0];
  const int*   ei  = (const int*)d_in[1];
  const float* W1  = (const float*)d_in[2];
  const float* as1 = (const float*)d_in[3];
  const float* ad1 = (const float*)d_in[4];
  const float* b1  = (const float*)d_in[5];
  const float* W2  = (const float*)d_in[6];
  const float* as2 = (const float*)d_in[7];
  const float* ad2 = (const float*)d_in[8];
  const float* b2  = (const float*)d_in[9];
  const float* fcW = (const float*)d_in[10];
  const float* fcb = (const float*)d_in[11];
  float* out = (float*)d_out;

  char* w = (char*)d_ws;
  size_t o = 0;
  auto alloc = [&](size_t bytes) {
    void* p = w + o;
    o = (o + bytes + 255) & ~(size_t)255;
    return p;
  };
  unsigned short* XPb  = (unsigned short*)alloc((size_t)N_NODES * 512 * 2);  // bf16 xp1
  unsigned short* XP2b = (unsigned short*)alloc((size_t)N_NODES * 256 * 2);  // bf16 xp2
  float* H   = (float*)alloc((size_t)N_NODES * 512 * 4);  // h1 (fp32) then h2 reuses
  float* aS1 = (float*)alloc((size_t)N_NODES * 2 * 4);
  float* aD1 = (float*)alloc((size_t)N_NODES * 2 * 4);
  float* aS2 = (float*)alloc((size_t)N_NODES * 4);
  float* aD2 = (float*)alloc((size_t)N_NODES * 4);
  int* cnt   = (int*)alloc((size_t)N_NODES * 4);
  int* offs  = (int*)alloc((size_t)(N_NODES + 1) * 4);
  int* pos   = (int*)alloc((size_t)(N_NODES + 1) * 4);
  int* csr   = (int*)alloc((size_t)E_TOT * 4);
  float* csum = (float*)alloc(256 * 4);

  // CSR build (shared by both layers)
  zero_k<<<(N_NODES + 255) / 256, 256, 0, stream>>>(cnt, csum);
  hist_k<<<(E_TOT + 255) / 256, 256, 0, stream>>>(ei, cnt);
  scan_k<<<1, 1024, 0, stream>>>(cnt, offs, pos);
  scatter_k<<<(E_TOT + 255) / 256, 256, 0, stream>>>(ei, pos, csr);

  // layer 1
  gemm_bf16out<<<dim3(512 / 128, (N_NODES + 127) / 128), 256, 0, stream>>>(
      x, W1, XPb, N_NODES, 512, IN_DIM);
  att_logits<2><<<(N_NODES * 2 + 3) / 4, 256, 0, stream>>>(XPb, as1, ad1, aS1, aD1);
  gat_agg<2><<<(N_NODES + 3) / 4, 256, 0, stream>>>(XPb, aS1, aD1, offs, csr, b1, H);

  // layer 2
  gemm_bf16out<<<dim3(256 / 128, (N_NODES + 127) / 128), 256, 0, stream>>>(
      H, W2, XP2b, N_NODES, 256, 512);
  att_logits<1><<<(N_NODES + 3) / 4, 256, 0, stream>>>(XP2b, as2, ad2, aS2, aD2);
  gat_agg<1><<<(N_NODES + 3) / 4, 256, 0, stream>>>(XP2b, aS2, aD2, offs, csr, b2, H);

  // mean over nodes + fc
  colsum_k<<<200, 256, 0, stream>>>(H, csum);
  final_k<<<1, 64, 0, stream>>>(csum, fcW, fcb, out);
}

// Round 7
// 488.561 us; speedup vs baseline: 1.7506x; 1.6440x over previous
//
#include <hip/hip_runtime.h>
#include <math.h>

#define N_NODES 50000
#define N_PAD   50048    // padded rows so OOB tile reads stay in-buffer
#define N_EDGES 400000
#define E_TOT   450000   // + self loops
#define IN_DIM  133
#define K1      160      // IN_DIM padded to /32
#define HID     256
#define NEG_SLOPE 0.2f

typedef unsigned int uint;
typedef unsigned short ushort;
typedef __attribute__((ext_vector_type(8))) short short8;
typedef __attribute__((ext_vector_type(4))) float f32x4;

// ---------------- bf16 helpers ----------------
__device__ __forceinline__ float bf_lo(uint u) { return __uint_as_float(u << 16); }
__device__ __forceinline__ float bf_hi(uint u) { return __uint_as_float(u & 0xffff0000u); }
__device__ __forceinline__ uint f2bf1(float f) {  // round-to-nearest-even
  uint u = __float_as_uint(f);
  return (u + 0x7fffu + ((u >> 16) & 1u)) >> 16;
}
__device__ __forceinline__ uint pack_bf2(float lo, float hi) {
  return f2bf1(lo) | (f2bf1(hi) << 16);
}

// ---------------- wave helpers (wave64) ----------------
__device__ __forceinline__ float wave_max(float v) {
#pragma unroll
  for (int m = 1; m < 64; m <<= 1) v = fmaxf(v, __shfl_xor(v, m));
  return v;
}
__device__ __forceinline__ float wave_sum(float v) {
#pragma unroll
  for (int m = 1; m < 64; m <<= 1) v += __shfl_xor(v, m);
  return v;
}

// ---------------- CSR build ----------------
__global__ void zero_k(int* __restrict__ cnt, float* __restrict__ csum) {
  int t = blockIdx.x * 256 + threadIdx.x;
  if (t < N_NODES) cnt[t] = 0;
  if (t < 256) csum[t] = 0.f;
}

__global__ void hist_k(const int* __restrict__ ei, int* __restrict__ cnt) {
  int e = blockIdx.x * 256 + threadIdx.x;
  if (e >= E_TOT) return;
  int dst = (e < N_EDGES) ? ei[N_EDGES + e] : (e - N_EDGES);
  atomicAdd(&cnt[dst], 1);
}

__global__ __launch_bounds__(1024) void scan_k(const int* __restrict__ cnt,
                                               int* __restrict__ offs,
                                               int* __restrict__ pos) {
  __shared__ int bs[1024];
  const int t = threadIdx.x;
  const int CHUNK = 49;
  const int base = t * CHUNK;
  int s = 0;
  for (int i = 0; i < CHUNK; ++i) {
    int idx = base + i;
    if (idx < N_NODES) s += cnt[idx];
  }
  bs[t] = s;
  __syncthreads();
  for (int off = 1; off < 1024; off <<= 1) {
    int v = 0;
    if (t >= off) v = bs[t - off];
    __syncthreads();
    if (t >= off) bs[t] += v;
    __syncthreads();
  }
  int run = (t > 0) ? bs[t - 1] : 0;
  for (int i = 0; i < CHUNK; ++i) {
    int idx = base + i;
    if (idx < N_NODES) {
      offs[idx] = run;
      pos[idx] = run;
      run += cnt[idx];
    }
  }
  if (t == 1023) offs[N_NODES] = bs[1023];
}

__global__ void scatter_k(const int* __restrict__ ei, int* __restrict__ pos,
                          int* __restrict__ csr_src) {
  int e = blockIdx.x * 256 + threadIdx.x;
  if (e >= E_TOT) return;
  int src, dst;
  if (e < N_EDGES) { src = ei[e]; dst = ei[N_EDGES + e]; }
  else             { src = e - N_EDGES; dst = src; }
  int p = atomicAdd(&pos[dst], 1);
  csr_src[p] = src;
}

// ---------------- fp32 -> bf16 converts / weight transposes ----------------
__global__ void conv_x_k(const float* __restrict__ x, ushort* __restrict__ xb) {
  // xb[N_PAD][K1]; zero pad rows>=N_NODES and cols>=IN_DIM
  int t = blockIdx.x * 256 + threadIdx.x;
  if (t >= N_PAD * (K1 / 2)) return;
  int r = t / (K1 / 2), cc = (t % (K1 / 2)) * 2;
  float v0 = 0.f, v1 = 0.f;
  if (r < N_NODES) {
    if (cc < IN_DIM) v0 = x[(size_t)r * IN_DIM + cc];
    if (cc + 1 < IN_DIM) v1 = x[(size_t)r * IN_DIM + cc + 1];
  }
  *(uint*)&xb[(size_t)r * K1 + cc] = pack_bf2(v0, v1);
}

__global__ void conv_w1t_k(const float* __restrict__ W1, ushort* __restrict__ w1t) {
  // w1t[512][K1] = W1[k][n]^T, zero pad k>=IN_DIM
  int t = blockIdx.x * 256 + threadIdx.x;
  if (t >= 512 * (K1 / 2)) return;
  int n = t / (K1 / 2), cc = (t % (K1 / 2)) * 2;
  float v0 = (cc < IN_DIM) ? W1[(size_t)cc * 512 + n] : 0.f;
  float v1 = (cc + 1 < IN_DIM) ? W1[(size_t)(cc + 1) * 512 + n] : 0.f;
  *(uint*)&w1t[(size_t)n * K1 + cc] = pack_bf2(v0, v1);
}

__global__ void conv_w2t_k(const float* __restrict__ W2, ushort* __restrict__ w2t) {
  // w2t[256][512] = W2[k][n]^T
  int t = blockIdx.x * 256 + threadIdx.x;
  if (t >= 256 * 256) return;
  int n = t / 256, cc = (t % 256) * 2;
  *(uint*)&w2t[(size_t)n * 512 + cc] =
      pack_bf2(W2[(size_t)cc * 256 + n], W2[(size_t)(cc + 1) * 256 + n]);
}

// ---------------- MFMA bf16 GEMM: C[M][N] = A[M][K] * BT[N][K]^T ------------
// 128x128 tile, 4 waves, each wave 64x64 via 4x4 of 16x16x32 frags.
// A/B frag: lane l -> row/col = l&15, k = 8*(l>>4)+j. C/D: col=l&15, row=(l>>4)*4+reg.
__device__ __forceinline__ void gload_lds16(const ushort* g, ushort* l) {
  __builtin_amdgcn_global_load_lds(
      (const __attribute__((address_space(1))) void*)g,
      (__attribute__((address_space(3))) void*)l, 16, 0, 0);
}

template <int KD>
__global__ __launch_bounds__(256) void gemm_mfma(
    const ushort* __restrict__ A,   // [>=M][KD] bf16 (rows padded to tile)
    const ushort* __restrict__ BT,  // [N][KD] bf16
    ushort* __restrict__ C,         // [M][N] bf16
    int M, int N) {
  __shared__ ushort As[128][32];
  __shared__ ushort Bs[128][32];
  const int bm = blockIdx.y * 128;
  const int bn = blockIdx.x * 128;
  const int tid = threadIdx.x;
  const int wv = tid >> 6, lane = tid & 63;
  const int wr = (wv >> 1) * 64;   // wave's row quadrant
  const int wc = (wv & 1) * 64;    // wave's col quadrant
  const int fr = lane & 15;
  const int fg = lane >> 4;
  // staging coords: thread t covers (row = t>>2, chunk = t&3) and row+64
  const int sr = tid >> 2;
  const int sc = (tid & 3) * 8;
  // wave-uniform LDS bases for global_load_lds (lane i lands at base + i*16B)
  ushort* a_lo = &As[wv * 16][0];
  ushort* b_lo = &Bs[wv * 16][0];

  f32x4 acc[4][4] = {};

  for (int k0 = 0; k0 < KD; k0 += 32) {
    gload_lds16(&A[(size_t)(bm + sr) * KD + k0 + sc], a_lo);
    gload_lds16(&A[(size_t)(bm + sr + 64) * KD + k0 + sc], &As[64 + wv * 16][0]);
    gload_lds16(&BT[(size_t)(bn + sr) * KD + k0 + sc], b_lo);
    gload_lds16(&BT[(size_t)(bn + sr + 64) * KD + k0 + sc], &Bs[64 + wv * 16][0]);
    __syncthreads();

    short8 af[4], bfr[4];
#pragma unroll
    for (int mi = 0; mi < 4; ++mi)
      af[mi] = *(const short8*)&As[wr + mi * 16 + fr][fg * 8];
#pragma unroll
    for (int ni = 0; ni < 4; ++ni)
      bfr[ni] = *(const short8*)&Bs[wc + ni * 16 + fr][fg * 8];
#pragma unroll
    for (int mi = 0; mi < 4; ++mi)
#pragma unroll
      for (int ni = 0; ni < 4; ++ni)
        acc[mi][ni] = __builtin_amdgcn_mfma_f32_16x16x32_bf16(
            af[mi], bfr[ni], acc[mi][ni], 0, 0, 0);
    __syncthreads();
  }

#pragma unroll
  for (int mi = 0; mi < 4; ++mi) {
#pragma unroll
    for (int ni = 0; ni < 4; ++ni) {
      const int col = bn + wc + ni * 16 + fr;
      const int row0 = bm + wr + mi * 16 + fg * 4;
#pragma unroll
      for (int t = 0; t < 4; ++t) {
        const int row = row0 + t;
        if (row < M) C[(size_t)row * N + col] = (ushort)f2bf1(acc[mi][ni][t]);
      }
    }
  }
}

// ---------------- per-(node,head) attention logits from bf16 xp ------------
template <int HEADS>
__global__ __launch_bounds__(256) void att_logits(
    const ushort* __restrict__ xpb, const float* __restrict__ att_src,
    const float* __restrict__ att_dst, float* __restrict__ a_s,
    float* __restrict__ a_d) {
  const int wid = (blockIdx.x << 2) + (threadIdx.x >> 6);
  const int lane = threadIdx.x & 63;
  if (wid >= N_NODES * HEADS) return;
  const int head = wid % HEADS;
  const uint2 xv = *(const uint2*)(xpb + (size_t)wid * HID + lane * 4);
  const float x0 = bf_lo(xv.x), x1 = bf_hi(xv.x), x2 = bf_lo(xv.y), x3 = bf_hi(xv.y);
  const float4 sv = *(const float4*)(att_src + head * HID + lane * 4);
  const float4 dv = *(const float4*)(att_dst + head * HID + lane * 4);
  float ps = x0 * sv.x + x1 * sv.y + x2 * sv.z + x3 * sv.w;
  float pd = x0 * dv.x + x1 * dv.y + x2 * dv.z + x3 * dv.w;
  ps = wave_sum(ps);
  pd = wave_sum(pd);
  if (lane == 0) { a_s[wid] = ps; a_d[wid] = pd; }
}

// ---------- fused segment softmax + bf16 gather-aggregate + bias + ELU -----
// HEADS==2: out is bf16 [node][512] (feeds MFMA gemm2). HEADS==1: fp32 [node][256].
template <int HEADS>
__global__ __launch_bounds__(256) void gat_agg(
    const ushort* __restrict__ xpb, const float* __restrict__ a_s,
    const float* __restrict__ a_d, const int* __restrict__ offs,
    const int* __restrict__ csr, const float* __restrict__ bias,
    void* __restrict__ outv) {
  const int node = (blockIdx.x << 2) + (threadIdx.x >> 6);
  const int lane = threadIdx.x & 63;
  if (node >= N_NODES) return;
  const int beg = offs[node], end = offs[node + 1];
  const int deg = end - beg;
  const float ad0 = a_d[node * HEADS + 0];
  const float ad1 = (HEADS == 2) ? a_d[node * HEADS + 1] : 0.f;

  if (deg <= 64) {
    int s = 0;
    float e0 = -INFINITY, e1 = -INFINITY;
    if (lane < deg) {
      s = csr[beg + lane];
      float v0 = a_s[s * HEADS + 0] + ad0;
      e0 = v0 > 0.f ? v0 : NEG_SLOPE * v0;
      if (HEADS == 2) {
        float v1 = a_s[s * HEADS + 1] + ad1;
        e1 = v1 > 0.f ? v1 : NEG_SLOPE * v1;
      }
    }
    const float m0 = wave_max(e0);
    const float p0 = (lane < deg) ? __expf(e0 - m0) : 0.f;
    const float z0 = wave_sum(p0);
    const float al0 = p0 / (z0 + 1e-16f);
    float al1 = 0.f;
    if (HEADS == 2) {
      const float m1 = wave_max(e1);
      const float p1 = (lane < deg) ? __expf(e1 - m1) : 0.f;
      const float z1 = wave_sum(p1);
      al1 = p1 / (z1 + 1e-16f);
    }

    if (HEADS == 2) {
      float acc[8] = {};
      for (int i = 0; i < deg; ++i) {
        int si = __shfl(s, i);
        float a0 = __shfl(al0, i);
        float a1 = __shfl(al1, i);
        float aa = (lane < 32) ? a0 : a1;
        uint4 v = *(const uint4*)(xpb + (size_t)si * 512 + lane * 8);
        acc[0] = fmaf(aa, bf_lo(v.x), acc[0]);
        acc[1] = fmaf(aa, bf_hi(v.x), acc[1]);
        acc[2] = fmaf(aa, bf_lo(v.y), acc[2]);
        acc[3] = fmaf(aa, bf_hi(v.y), acc[3]);
        acc[4] = fmaf(aa, bf_lo(v.z), acc[4]);
        acc[5] = fmaf(aa, bf_hi(v.z), acc[5]);
        acc[6] = fmaf(aa, bf_lo(v.w), acc[6]);
        acc[7] = fmaf(aa, bf_hi(v.w), acc[7]);
      }
      const int col = lane * 8;
      const float4 b0 = *(const float4*)(bias + col);
      const float4 b1 = *(const float4*)(bias + col + 4);
      float o[8];
      o[0] = acc[0] + b0.x; o[1] = acc[1] + b0.y; o[2] = acc[2] + b0.z; o[3] = acc[3] + b0.w;
      o[4] = acc[4] + b1.x; o[5] = acc[5] + b1.y; o[6] = acc[6] + b1.z; o[7] = acc[7] + b1.w;
#pragma unroll
      for (int j = 0; j < 8; ++j) o[j] = o[j] > 0.f ? o[j] : __expf(o[j]) - 1.f;
      uint4 w;
      w.x = pack_bf2(o[0], o[1]); w.y = pack_bf2(o[2], o[3]);
      w.z = pack_bf2(o[4], o[5]); w.w = pack_bf2(o[6], o[7]);
      *(uint4*)((ushort*)outv + (size_t)node * 512 + col) = w;
    } else {
      float acc[4] = {};
      for (int i = 0; i < deg; ++i) {
        int si = __shfl(s, i);
        float aa = __shfl(al0, i);
        uint2 v = *(const uint2*)(xpb + (size_t)si * 256 + lane * 4);
        acc[0] = fmaf(aa, bf_lo(v.x), acc[0]);
        acc[1] = fmaf(aa, bf_hi(v.x), acc[1]);
        acc[2] = fmaf(aa, bf_lo(v.y), acc[2]);
        acc[3] = fmaf(aa, bf_hi(v.y), acc[3]);
      }
      const int col = lane * 4;
      const float4 bb = *(const float4*)(bias + col);
      float o0 = acc[0] + bb.x, o1 = acc[1] + bb.y, o2 = acc[2] + bb.z, o3 = acc[3] + bb.w;
      o0 = o0 > 0.f ? o0 : __expf(o0) - 1.f;
      o1 = o1 > 0.f ? o1 : __expf(o1) - 1.f;
      o2 = o2 > 0.f ? o2 : __expf(o2) - 1.f;
      o3 = o3 > 0.f ? o3 : __expf(o3) - 1.f;
      *(float4*)((float*)outv + (size_t)node * 256 + col) = make_float4(o0, o1, o2, o3);
    }
  } else {
    // rare fallback (deg > 64): 3-pass per head
    for (int h = 0; h < HEADS; ++h) {
      const float adh = (h == 0) ? ad0 : ad1;
      float m = -INFINITY;
      for (int i = beg + lane; i < end; i += 64) {
        int s2 = csr[i];
        float e = a_s[s2 * HEADS + h] + adh;
        e = e > 0.f ? e : NEG_SLOPE * e;
        m = fmaxf(m, e);
      }
      m = wave_max(m);
      float z = 0.f;
      for (int i = beg + lane; i < end; i += 64) {
        int s2 = csr[i];
        float e = a_s[s2 * HEADS + h] + adh;
        e = e > 0.f ? e : NEG_SLOPE * e;
        z += __expf(e - m);
      }
      z = wave_sum(z) + 1e-16f;
      const float invz = 1.f / z;
      float acc[4] = {};
      for (int i = beg; i < end; ++i) {
        int s2 = csr[i];
        float e = a_s[s2 * HEADS + h] + adh;
        e = e > 0.f ? e : NEG_SLOPE * e;
        float al = __expf(e - m) * invz;
        uint2 v = *(const uint2*)(xpb + ((size_t)s2 * HEADS + h) * HID + lane * 4);
        acc[0] = fmaf(al, bf_lo(v.x), acc[0]);
        acc[1] = fmaf(al, bf_hi(v.x), acc[1]);
        acc[2] = fmaf(al, bf_lo(v.y), acc[2]);
        acc[3] = fmaf(al, bf_hi(v.y), acc[3]);
      }
      const int oc = h * HID + lane * 4;
      const float4 bb = *(const float4*)(bias + oc);
      float o0 = acc[0] + bb.x, o1 = acc[1] + bb.y, o2 = acc[2] + bb.z, o3 = acc[3] + bb.w;
      o0 = o0 > 0.f ? o0 : __expf(o0) - 1.f;
      o1 = o1 > 0.f ? o1 : __expf(o1) - 1.f;
      o2 = o2 > 0.f ? o2 : __expf(o2) - 1.f;
      o3 = o3 > 0.f ? o3 : __expf(o3) - 1.f;
      if (HEADS == 2) {
        uint2 w = make_uint2(pack_bf2(o0, o1), pack_bf2(o2, o3));
        *(uint2*)((ushort*)outv + (size_t)node * 512 + oc) = w;
      } else {
        *(float4*)((float*)outv + (size_t)node * 256 + oc) = make_float4(o0, o1, o2, o3);
      }
    }
  }
}

// ---------------- mean over nodes + fc head ----------------
__global__ void colsum_k(const float* __restrict__ h2, float* __restrict__ sum) {
  const int c = threadIdx.x;
  const int r0 = blockIdx.x * 250;
  float s = 0.f;
  for (int r = r0; r < r0 + 250; ++r) s += h2[(size_t)r * HID + c];
  atomicAdd(&sum[c], s);
}

__global__ void final_k(const float* __restrict__ csum, const float* __restrict__ fcW,
                        const float* __restrict__ fcb, float* __restrict__ out) {
  const int lane = threadIdx.x;
  float p0 = 0.f, p1 = 0.f, p2 = 0.f;
  for (int c = lane; c < HID; c += 64) {
    float v = csum[c] * (1.f / (float)N_NODES);
    p0 = fmaf(v, fcW[c * 3 + 0], p0);
    p1 = fmaf(v, fcW[c * 3 + 1], p1);
    p2 = fmaf(v, fcW[c * 3 + 2], p2);
  }
  p0 = wave_sum(p0); p1 = wave_sum(p1); p2 = wave_sum(p2);
  if (lane == 0) {
    out[0] = p0 + fcb[0];
    out[1] = p1 + fcb[1];
    out[2] = p2 + fcb[2];
  }
}

// ---------------- launch ----------------
extern "C" void kernel_launch(void* const* d_in, const int* in_sizes, int n_in,
                              void* d_out, int out_size, void* d_ws, size_t ws_size,
                              hipStream_t stream) {
  const float* x   = (const float*)d_in[0];
  const int*   ei  = (const int*)d_in[1];
  const float* W1  = (const float*)d_in[2];
  const float* as1 = (const float*)d_in[3];
  const float* ad1 = (const float*)d_in[4];
  const float* b1  = (const float*)d_in[5];
  const float* W2  = (const float*)d_in[6];
  const float* as2 = (const float*)d_in[7];
  const float* ad2 = (const float*)d_in[8];
  const float* b2  = (const float*)d_in[9];
  const float* fcW = (const float*)d_in[10];
  const float* fcb = (const float*)d_in[11];
  float* out = (float*)d_out;

  char* w = (char*)d_ws;
  size_t o = 0;
  auto alloc = [&](size_t bytes) {
    void* p = w + o;
    o = (o + bytes + 255) & ~(size_t)255;
    return p;
  };
  ushort* XB   = (ushort*)alloc((size_t)N_PAD * K1 * 2);    // x bf16, padded
  ushort* W1T  = (ushort*)alloc((size_t)512 * K1 * 2);      // W1^T bf16
  ushort* W2T  = (ushort*)alloc((size_t)256 * 512 * 2);     // W2^T bf16
  ushort* XPb  = (ushort*)alloc((size_t)N_NODES * 512 * 2); // xp1 bf16
  ushort* H1b  = (ushort*)alloc((size_t)N_PAD * 512 * 2);   // h1 bf16 (gemm2 A)
  ushort* XP2b = (ushort*)alloc((size_t)N_NODES * 256 * 2); // xp2 bf16
  float*  H2   = (float*)alloc((size_t)N_NODES * 256 * 4);  // h2 fp32
  float* aS1 = (float*)alloc((size_t)N_NODES * 2 * 4);
  float* aD1 = (float*)alloc((size_t)N_NODES * 2 * 4);
  float* aS2 = (float*)alloc((size_t)N_NODES * 4);
  float* aD2 = (float*)alloc((size_t)N_NODES * 4);
  int* cnt   = (int*)alloc((size_t)N_NODES * 4);
  int* offs  = (int*)alloc((size_t)(N_NODES + 1) * 4);
  int* pos   = (int*)alloc((size_t)(N_NODES + 1) * 4);
  int* csr   = (int*)alloc((size_t)E_TOT * 4);
  float* csum = (float*)alloc(256 * 4);

  // CSR build + input converts
  zero_k<<<(N_NODES + 255) / 256, 256, 0, stream>>>(cnt, csum);
  hist_k<<<(E_TOT + 255) / 256, 256, 0, stream>>>(ei, cnt);
  scan_k<<<1, 1024, 0, stream>>>(cnt, offs, pos);
  scatter_k<<<(E_TOT + 255) / 256, 256, 0, stream>>>(ei, pos, csr);
  conv_x_k<<<(N_PAD * (K1 / 2) + 255) / 256, 256, 0, stream>>>(x, XB);
  conv_w1t_k<<<(512 * (K1 / 2) + 255) / 256, 256, 0, stream>>>(W1, W1T);
  conv_w2t_k<<<(256 * 256 + 255) / 256, 256, 0, stream>>>(W2, W2T);

  // layer 1: XP1 = XB @ W1  (MFMA bf16)
  gemm_mfma<K1><<<dim3(512 / 128, (N_NODES + 127) / 128), 256, 0, stream>>>(
      XB, W1T, XPb, N_NODES, 512);
  att_logits<2><<<(N_NODES * 2 + 3) / 4, 256, 0, stream>>>(XPb, as1, ad1, aS1, aD1);
  gat_agg<2><<<(N_NODES + 3) / 4, 256, 0, stream>>>(XPb, aS1, aD1, offs, csr, b1, H1b);

  // layer 2: XP2 = H1 @ W2  (MFMA bf16)
  gemm_mfma<512><<<dim3(256 / 128, (N_NODES + 127) / 128), 256, 0, stream>>>(
      H1b, W2T, XP2b, N_NODES, 256);
  att_logits<1><<<(N_NODES + 3) / 4, 256, 0, stream>>>(XP2b, as2, ad2, aS2, aD2);
  gat_agg<1><<<(N_NODES + 3) / 4, 256, 0, stream>>>(XP2b, aS2, aD2, offs, csr, b2, H2);

  // mean over nodes + fc
  colsum_k<<<200, 256, 0, stream>>>(H2, csum);
  final_k<<<1, 64, 0, stream>>>(csum, fcW, fcb, out);
}

// Round 15
// 371.616 us; speedup vs baseline: 2.3015x; 1.3147x over previous
//
#include <hip/hip_runtime.h>
#include <math.h>

#define N_NODES 50000
#define N_PAD   50048    // padded rows so OOB tile reads stay in-buffer
#define N_EDGES 400000
#define E_TOT   450000   // + self loops
#define IN_DIM  133
#define K1      160      // IN_DIM padded to /32
#define HID     256
#define NEG_SLOPE 0.2f
#define SCAN_BLOCKS 196  // 196*256 = 50176 >= 50000

typedef unsigned int uint;
typedef unsigned short ushort;
typedef __attribute__((ext_vector_type(8))) short short8;
typedef __attribute__((ext_vector_type(4))) float f32x4;

// ---------------- bf16 helpers ----------------
__device__ __forceinline__ float bf_lo(uint u) { return __uint_as_float(u << 16); }
__device__ __forceinline__ float bf_hi(uint u) { return __uint_as_float(u & 0xffff0000u); }
__device__ __forceinline__ uint f2bf1(float f) {  // round-to-nearest-even
  uint u = __float_as_uint(f);
  return (u + 0x7fffu + ((u >> 16) & 1u)) >> 16;
}
__device__ __forceinline__ uint pack_bf2(float lo, float hi) {
  return f2bf1(lo) | (f2bf1(hi) << 16);
}

// ---------------- wave helpers (wave64) ----------------
__device__ __forceinline__ float wave_max(float v) {
#pragma unroll
  for (int m = 1; m < 64; m <<= 1) v = fmaxf(v, __shfl_xor(v, m));
  return v;
}
__device__ __forceinline__ float wave_sum(float v) {
#pragma unroll
  for (int m = 1; m < 64; m <<= 1) v += __shfl_xor(v, m);
  return v;
}

// ---------------- CSR build ----------------
__global__ void zero_k(int* __restrict__ cnt, float* __restrict__ csum) {
  int t = blockIdx.x * 256 + threadIdx.x;
  if (t < N_NODES) cnt[t] = 0;
  if (t < 256) csum[t] = 0.f;
}

__global__ void hist_k(const int* __restrict__ ei, int* __restrict__ cnt) {
  int e = blockIdx.x * 256 + threadIdx.x;
  if (e >= E_TOT) return;
  int dst = (e < N_EDGES) ? ei[N_EDGES + e] : (e - N_EDGES);
  atomicAdd(&cnt[dst], 1);
}

// hierarchical exclusive scan of cnt[50000] -> offs/pos (3 parallel kernels)
__global__ void scan1_k(const int* __restrict__ cnt, int* __restrict__ bsum) {
  __shared__ int sh[256];
  const int t = threadIdx.x, b = blockIdx.x;
  const int idx = b * 256 + t;
  sh[t] = (idx < N_NODES) ? cnt[idx] : 0;
  __syncthreads();
  for (int off = 128; off > 0; off >>= 1) {
    if (t < off) sh[t] += sh[t + off];
    __syncthreads();
  }
  if (t == 0) bsum[b] = sh[0];
}

__global__ void scan2_k(const int* __restrict__ bsum, int* __restrict__ boff) {
  __shared__ int sh[256];
  const int t = threadIdx.x;
  sh[t] = (t < SCAN_BLOCKS) ? bsum[t] : 0;
  __syncthreads();
  for (int off = 1; off < 256; off <<= 1) {
    int v = (t >= off) ? sh[t - off] : 0;
    __syncthreads();
    sh[t] += v;
    __syncthreads();
  }
  if (t < SCAN_BLOCKS) boff[t] = (t > 0) ? sh[t - 1] : 0;  // exclusive
}

__global__ void scan3_k(const int* __restrict__ cnt, const int* __restrict__ boff,
                        int* __restrict__ offs, int* __restrict__ pos) {
  __shared__ int sh[256];
  const int t = threadIdx.x, b = blockIdx.x;
  const int idx = b * 256 + t;
  const int v = (idx < N_NODES) ? cnt[idx] : 0;
  sh[t] = v;
  __syncthreads();
  for (int off = 1; off < 256; off <<= 1) {
    int u = (t >= off) ? sh[t - off] : 0;
    __syncthreads();
    sh[t] += u;
    __syncthreads();
  }
  const int ex = sh[t] - v + boff[b];  // exclusive prefix
  if (idx < N_NODES) { offs[idx] = ex; pos[idx] = ex; }
  if (idx == N_NODES - 1) offs[N_NODES] = ex + v;  // == E_TOT
}

__global__ void scatter_k(const int* __restrict__ ei, int* __restrict__ pos,
                          int* __restrict__ csr_src) {
  int e = blockIdx.x * 256 + threadIdx.x;
  if (e >= E_TOT) return;
  int src, dst;
  if (e < N_EDGES) { src = ei[e]; dst = ei[N_EDGES + e]; }
  else             { src = e - N_EDGES; dst = src; }
  int p = atomicAdd(&pos[dst], 1);
  csr_src[p] = src;
}

// ---------------- fp32 -> bf16 converts / weight transposes ----------------
__global__ void conv_x_k(const float* __restrict__ x, ushort* __restrict__ xb) {
  // xb[N_PAD][K1]; zero pad rows>=N_NODES and cols>=IN_DIM
  int t = blockIdx.x * 256 + threadIdx.x;
  if (t >= N_PAD * (K1 / 2)) return;
  int r = t / (K1 / 2), cc = (t % (K1 / 2)) * 2;
  float v0 = 0.f, v1 = 0.f;
  if (r < N_NODES) {
    if (cc < IN_DIM) v0 = x[(size_t)r * IN_DIM + cc];
    if (cc + 1 < IN_DIM) v1 = x[(size_t)r * IN_DIM + cc + 1];
  }
  *(uint*)&xb[(size_t)r * K1 + cc] = pack_bf2(v0, v1);
}

__global__ void conv_w1t_k(const float* __restrict__ W1, ushort* __restrict__ w1t) {
  // w1t[512][K1] = W1[k][n]^T, zero pad k>=IN_DIM
  int t = blockIdx.x * 256 + threadIdx.x;
  if (t >= 512 * (K1 / 2)) return;
  int n = t / (K1 / 2), cc = (t % (K1 / 2)) * 2;
  float v0 = (cc < IN_DIM) ? W1[(size_t)cc * 512 + n] : 0.f;
  float v1 = (cc + 1 < IN_DIM) ? W1[(size_t)(cc + 1) * 512 + n] : 0.f;
  *(uint*)&w1t[(size_t)n * K1 + cc] = pack_bf2(v0, v1);
}

__global__ void conv_w2t_k(const float* __restrict__ W2, ushort* __restrict__ w2t) {
  // w2t[256][512] = W2[k][n]^T
  int t = blockIdx.x * 256 + threadIdx.x;
  if (t >= 256 * 256) return;
  int n = t / 256, cc = (t % 256) * 2;
  *(uint*)&w2t[(size_t)n * 512 + cc] =
      pack_bf2(W2[(size_t)cc * 256 + n], W2[(size_t)(cc + 1) * 256 + n]);
}

// ---------------- MFMA bf16 GEMM: C[M][N] = A[M][K] * BT[N][K]^T ------------
// 128x128 tile, 4 waves, each wave 64x64 via 4x4 of 16x16x32 frags.
// A/B frag: lane l -> row/col = l&15, k = 8*(l>>4)+j. C/D: col=l&15, row=(l>>4)*4+reg.
__device__ __forceinline__ void gload_lds16(const ushort* g, ushort* l) {
  __builtin_amdgcn_global_load_lds(
      (const __attribute__((address_space(1))) void*)g,
      (__attribute__((address_space(3))) void*)l, 16, 0, 0);
}

template <int KD>
__global__ __launch_bounds__(256) void gemm_mfma(
    const ushort* __restrict__ A,   // [>=M][KD] bf16 (rows padded to tile)
    const ushort* __restrict__ BT,  // [N][KD] bf16
    ushort* __restrict__ C,         // [M][N] bf16
    int M, int N) {
  __shared__ ushort As[128][32];
  __shared__ ushort Bs[128][32];
  const int bm = blockIdx.y * 128;
  const int bn = blockIdx.x * 128;
  const int tid = threadIdx.x;
  const int wv = tid >> 6, lane = tid & 63;
  const int wr = (wv >> 1) * 64;   // wave's row quadrant
  const int wc = (wv & 1) * 64;    // wave's col quadrant
  const int fr = lane & 15;
  const int fg = lane >> 4;
  // staging coords: thread t covers (row = t>>2, chunk = t&3) and row+64
  const int sr = tid >> 2;
  const int sc = (tid & 3) * 8;
  // wave-uniform LDS bases for global_load_lds (lane i lands at base + i*16B)
  ushort* a_lo = &As[wv * 16][0];
  ushort* b_lo = &Bs[wv * 16][0];

  f32x4 acc[4][4] = {};

  for (int k0 = 0; k0 < KD; k0 += 32) {
    gload_lds16(&A[(size_t)(bm + sr) * KD + k0 + sc], a_lo);
    gload_lds16(&A[(size_t)(bm + sr + 64) * KD + k0 + sc], &As[64 + wv * 16][0]);
    gload_lds16(&BT[(size_t)(bn + sr) * KD + k0 + sc], b_lo);
    gload_lds16(&BT[(size_t)(bn + sr + 64) * KD + k0 + sc], &Bs[64 + wv * 16][0]);
    __syncthreads();

    short8 af[4], bfr[4];
#pragma unroll
    for (int mi = 0; mi < 4; ++mi)
      af[mi] = *(const short8*)&As[wr + mi * 16 + fr][fg * 8];
#pragma unroll
    for (int ni = 0; ni < 4; ++ni)
      bfr[ni] = *(const short8*)&Bs[wc + ni * 16 + fr][fg * 8];
#pragma unroll
    for (int mi = 0; mi < 4; ++mi)
#pragma unroll
      for (int ni = 0; ni < 4; ++ni)
        acc[mi][ni] = __builtin_amdgcn_mfma_f32_16x16x32_bf16(
            af[mi], bfr[ni], acc[mi][ni], 0, 0, 0);
    __syncthreads();
  }

#pragma unroll
  for (int mi = 0; mi < 4; ++mi) {
#pragma unroll
    for (int ni = 0; ni < 4; ++ni) {
      const int col = bn + wc + ni * 16 + fr;
      const int row0 = bm + wr + mi * 16 + fg * 4;
#pragma unroll
      for (int t = 0; t < 4; ++t) {
        const int row = row0 + t;
        if (row < M) C[(size_t)row * N + col] = (ushort)f2bf1(acc[mi][ni][t]);
      }
    }
  }
}

// ---------------- per-(node,head) attention logits from bf16 xp ------------
template <int HEADS>
__global__ __launch_bounds__(256) void att_logits(
    const ushort* __restrict__ xpb, const float* __restrict__ att_src,
    const float* __restrict__ att_dst, float* __restrict__ a_s,
    float* __restrict__ a_d) {
  const int wid = (blockIdx.x << 2) + (threadIdx.x >> 6);
  const int lane = threadIdx.x & 63;
  if (wid >= N_NODES * HEADS) return;
  const int head = wid % HEADS;
  const uint2 xv = *(const uint2*)(xpb + (size_t)wid * HID + lane * 4);
  const float x0 = bf_lo(xv.x), x1 = bf_hi(xv.x), x2 = bf_lo(xv.y), x3 = bf_hi(xv.y);
  const float4 sv = *(const float4*)(att_src + head * HID + lane * 4);
  const float4 dv = *(const float4*)(att_dst + head * HID + lane * 4);
  float ps = x0 * sv.x + x1 * sv.y + x2 * sv.z + x3 * sv.w;
  float pd = x0 * dv.x + x1 * dv.y + x2 * dv.z + x3 * dv.w;
  ps = wave_sum(ps);
  pd = wave_sum(pd);
  if (lane == 0) { a_s[wid] = ps; a_d[wid] = pd; }
}

// ---------- fused segment softmax + bf16 gather-aggregate + bias + ELU -----
// HEADS==2: out is bf16 [node][512] (feeds MFMA gemm2). HEADS==1: fp32 [node][256].
template <int HEADS>
__global__ __launch_bounds__(256) void gat_agg(
    const ushort* __restrict__ xpb, const float* __restrict__ a_s,
    const float* __restrict__ a_d, const int* __restrict__ offs,
    const int* __restrict__ csr, const float* __restrict__ bias,
    void* __restrict__ outv) {
  const int node = (blockIdx.x << 2) + (threadIdx.x >> 6);
  const int lane = threadIdx.x & 63;
  if (node >= N_NODES) return;
  const int beg = offs[node], end = offs[node + 1];
  const int deg = end - beg;
  const float ad0 = a_d[node * HEADS + 0];
  const float ad1 = (HEADS == 2) ? a_d[node * HEADS + 1] : 0.f;

  if (deg <= 64) {
    int s = 0;
    float e0 = -INFINITY, e1 = -INFINITY;
    if (lane < deg) {
      s = csr[beg + lane];
      float v0 = a_s[s * HEADS + 0] + ad0;
      e0 = v0 > 0.f ? v0 : NEG_SLOPE * v0;
      if (HEADS == 2) {
        float v1 = a_s[s * HEADS + 1] + ad1;
        e1 = v1 > 0.f ? v1 : NEG_SLOPE * v1;
      }
    }
    const float m0 = wave_max(e0);
    const float p0 = (lane < deg) ? __expf(e0 - m0) : 0.f;
    const float z0 = wave_sum(p0);
    const float al0 = p0 / (z0 + 1e-16f);
    float al1 = 0.f;
    if (HEADS == 2) {
      const float m1 = wave_max(e1);
      const float p1 = (lane < deg) ? __expf(e1 - m1) : 0.f;
      const float z1 = wave_sum(p1);
      al1 = p1 / (z1 + 1e-16f);
    }

    if (HEADS == 2) {
      float acc[8] = {};
      for (int i = 0; i < deg; ++i) {
        int si = __shfl(s, i);
        float a0 = __shfl(al0, i);
        float a1 = __shfl(al1, i);
        float aa = (lane < 32) ? a0 : a1;
        uint4 v = *(const uint4*)(xpb + (size_t)si * 512 + lane * 8);
        acc[0] = fmaf(aa, bf_lo(v.x), acc[0]);
        acc[1] = fmaf(aa, bf_hi(v.x), acc[1]);
        acc[2] = fmaf(aa, bf_lo(v.y), acc[2]);
        acc[3] = fmaf(aa, bf_hi(v.y), acc[3]);
        acc[4] = fmaf(aa, bf_lo(v.z), acc[4]);
        acc[5] = fmaf(aa, bf_hi(v.z), acc[5]);
        acc[6] = fmaf(aa, bf_lo(v.w), acc[6]);
        acc[7] = fmaf(aa, bf_hi(v.w), acc[7]);
      }
      const int col = lane * 8;
      const float4 b0 = *(const float4*)(bias + col);
      const float4 b1 = *(const float4*)(bias + col + 4);
      float o[8];
      o[0] = acc[0] + b0.x; o[1] = acc[1] + b0.y; o[2] = acc[2] + b0.z; o[3] = acc[3] + b0.w;
      o[4] = acc[4] + b1.x; o[5] = acc[5] + b1.y; o[6] = acc[6] + b1.z; o[7] = acc[7] + b1.w;
#pragma unroll
      for (int j = 0; j < 8; ++j) o[j] = o[j] > 0.f ? o[j] : __expf(o[j]) - 1.f;
      uint4 w;
      w.x = pack_bf2(o[0], o[1]); w.y = pack_bf2(o[2], o[3]);
      w.z = pack_bf2(o[4], o[5]); w.w = pack_bf2(o[6], o[7]);
      *(uint4*)((ushort*)outv + (size_t)node * 512 + col) = w;
    } else {
      float acc[4] = {};
      for (int i = 0; i < deg; ++i) {
        int si = __shfl(s, i);
        float aa = __shfl(al0, i);
        uint2 v = *(const uint2*)(xpb + (size_t)si * 256 + lane * 4);
        acc[0] = fmaf(aa, bf_lo(v.x), acc[0]);
        acc[1] = fmaf(aa, bf_hi(v.x), acc[1]);
        acc[2] = fmaf(aa, bf_lo(v.y), acc[2]);
        acc[3] = fmaf(aa, bf_hi(v.y), acc[3]);
      }
      const int col = lane * 4;
      const float4 bb = *(const float4*)(bias + col);
      float o0 = acc[0] + bb.x, o1 = acc[1] + bb.y, o2 = acc[2] + bb.z, o3 = acc[3] + bb.w;
      o0 = o0 > 0.f ? o0 : __expf(o0) - 1.f;
      o1 = o1 > 0.f ? o1 : __expf(o1) - 1.f;
      o2 = o2 > 0.f ? o2 : __expf(o2) - 1.f;
      o3 = o3 > 0.f ? o3 : __expf(o3) - 1.f;
      *(float4*)((float*)outv + (size_t)node * 256 + col) = make_float4(o0, o1, o2, o3);
    }
  } else {
    // rare fallback (deg > 64): 3-pass per head
    for (int h = 0; h < HEADS; ++h) {
      const float adh = (h == 0) ? ad0 : ad1;
      float m = -INFINITY;
      for (int i = beg + lane; i < end; i += 64) {
        int s2 = csr[i];
        float e = a_s[s2 * HEADS + h] + adh;
        e = e > 0.f ? e : NEG_SLOPE * e;
        m = fmaxf(m, e);
      }
      m = wave_max(m);
      float z = 0.f;
      for (int i = beg + lane; i < end; i += 64) {
        int s2 = csr[i];
        float e = a_s[s2 * HEADS + h] + adh;
        e = e > 0.f ? e : NEG_SLOPE * e;
        z += __expf(e - m);
      }
      z = wave_sum(z) + 1e-16f;
      const float invz = 1.f / z;
      float acc[4] = {};
      for (int i = beg; i < end; ++i) {
        int s2 = csr[i];
        float e = a_s[s2 * HEADS + h] + adh;
        e = e > 0.f ? e : NEG_SLOPE * e;
        float al = __expf(e - m) * invz;
        uint2 v = *(const uint2*)(xpb + ((size_t)s2 * HEADS + h) * HID + lane * 4);
        acc[0] = fmaf(al, bf_lo(v.x), acc[0]);
        acc[1] = fmaf(al, bf_hi(v.x), acc[1]);
        acc[2] = fmaf(al, bf_lo(v.y), acc[2]);
        acc[3] = fmaf(al, bf_hi(v.y), acc[3]);
      }
      const int oc = h * HID + lane * 4;
      const float4 bb = *(const float4*)(bias + oc);
      float o0 = acc[0] + bb.x, o1 = acc[1] + bb.y, o2 = acc[2] + bb.z, o3 = acc[3] + bb.w;
      o0 = o0 > 0.f ? o0 : __expf(o0) - 1.f;
      o1 = o1 > 0.f ? o1 : __expf(o1) - 1.f;
      o2 = o2 > 0.f ? o2 : __expf(o2) - 1.f;
      o3 = o3 > 0.f ? o3 : __expf(o3) - 1.f;
      if (HEADS == 2) {
        uint2 w = make_uint2(pack_bf2(o0, o1), pack_bf2(o2, o3));
        *(uint2*)((ushort*)outv + (size_t)node * 512 + oc) = w;
      } else {
        *(float4*)((float*)outv + (size_t)node * 256 + oc) = make_float4(o0, o1, o2, o3);
      }
    }
  }
}

// ---------------- mean over nodes + fc head ----------------
__global__ void colsum_k(const float* __restrict__ h2, float* __restrict__ sum) {
  const int c = threadIdx.x;
  const int r0 = blockIdx.x * 250;
  float s = 0.f;
  for (int r = r0; r < r0 + 250; ++r) s += h2[(size_t)r * HID + c];
  atomicAdd(&sum[c], s);
}

__global__ void final_k(const float* __restrict__ csum, const float* __restrict__ fcW,
                        const float* __restrict__ fcb, float* __restrict__ out) {
  const int lane = threadIdx.x;
  float p0 = 0.f, p1 = 0.f, p2 = 0.f;
  for (int c = lane; c < HID; c += 64) {
    float v = csum[c] * (1.f / (float)N_NODES);
    p0 = fmaf(v, fcW[c * 3 + 0], p0);
    p1 = fmaf(v, fcW[c * 3 + 1], p1);
    p2 = fmaf(v, fcW[c * 3 + 2], p2);
  }
  p0 = wave_sum(p0); p1 = wave_sum(p1); p2 = wave_sum(p2);
  if (lane == 0) {
    out[0] = p0 + fcb[0];
    out[1] = p1 + fcb[1];
    out[2] = p2 + fcb[2];
  }
}

// ---------------- launch ----------------
extern "C" void kernel_launch(void* const* d_in, const int* in_sizes, int n_in,
                              void* d_out, int out_size, void* d_ws, size_t ws_size,
                              hipStream_t stream) {
  const float* x   = (const float*)d_in[0];
  const int*   ei  = (const int*)d_in[1];
  const float* W1  = (const float*)d_in[2];
  const float* as1 = (const float*)d_in[3];
  const float* ad1 = (const float*)d_in[4];
  const float* b1  = (const float*)d_in[5];
  const float* W2  = (const float*)d_in[6];
  const float* as2 = (const float*)d_in[7];
  const float* ad2 = (const float*)d_in[8];
  const float* b2  = (const float*)d_in[9];
  const float* fcW = (const float*)d_in[10];
  const float* fcb = (const float*)d_in[11];
  float* out = (float*)d_out;

  char* w = (char*)d_ws;
  size_t o = 0;
  auto alloc = [&](size_t bytes) {
    void* p = w + o;
    o = (o + bytes + 255) & ~(size_t)255;
    return p;
  };
  ushort* XB   = (ushort*)alloc((size_t)N_PAD * K1 * 2);    // x bf16, padded
  ushort* W1T  = (ushort*)alloc((size_t)512 * K1 * 2);      // W1^T bf16
  ushort* W2T  = (ushort*)alloc((size_t)256 * 512 * 2);     // W2^T bf16
  ushort* XPb  = (ushort*)alloc((size_t)N_NODES * 512 * 2); // xp1 bf16
  ushort* H1b  = (ushort*)alloc((size_t)N_PAD * 512 * 2);   // h1 bf16 (gemm2 A)
  ushort* XP2b = (ushort*)alloc((size_t)N_NODES * 256 * 2); // xp2 bf16
  float*  H2   = (float*)alloc((size_t)N_NODES * 256 * 4);  // h2 fp32
  float* aS1 = (float*)alloc((size_t)N_NODES * 2 * 4);
  float* aD1 = (float*)alloc((size_t)N_NODES * 2 * 4);
  float* aS2 = (float*)alloc((size_t)N_NODES * 4);
  float* aD2 = (float*)alloc((size_t)N_NODES * 4);
  int* cnt   = (int*)alloc((size_t)N_NODES * 4);
  int* offs  = (int*)alloc((size_t)(N_NODES + 1) * 4);
  int* pos   = (int*)alloc((size_t)(N_NODES + 1) * 4);
  int* csr   = (int*)alloc((size_t)E_TOT * 4);
  int* bsum  = (int*)alloc((size_t)SCAN_BLOCKS * 4);
  int* boff  = (int*)alloc((size_t)SCAN_BLOCKS * 4);
  float* csum = (float*)alloc(256 * 4);

  // CSR build + input converts
  zero_k<<<(N_NODES + 255) / 256, 256, 0, stream>>>(cnt, csum);
  hist_k<<<(E_TOT + 255) / 256, 256, 0, stream>>>(ei, cnt);
  scan1_k<<<SCAN_BLOCKS, 256, 0, stream>>>(cnt, bsum);
  scan2_k<<<1, 256, 0, stream>>>(bsum, boff);
  scan3_k<<<SCAN_BLOCKS, 256, 0, stream>>>(cnt, boff, offs, pos);
  scatter_k<<<(E_TOT + 255) / 256, 256, 0, stream>>>(ei, pos, csr);
  conv_x_k<<<(N_PAD * (K1 / 2) + 255) / 256, 256, 0, stream>>>(x, XB);
  conv_w1t_k<<<(512 * (K1 / 2) + 255) / 256, 256, 0, stream>>>(W1, W1T);
  conv_w2t_k<<<(256 * 256 + 255) / 256, 256, 0, stream>>>(W2, W2T);

  // layer 1: XP1 = XB @ W1  (MFMA bf16)
  gemm_mfma<K1><<<dim3(512 / 128, (N_NODES + 127) / 128), 256, 0, stream>>>(
      XB, W1T, XPb, N_NODES, 512);
  att_logits<2><<<(N_NODES * 2 + 3) / 4, 256, 0, stream>>>(XPb, as1, ad1, aS1, aD1);
  gat_agg<2><<<(N_NODES + 3) / 4, 256, 0, stream>>>(XPb, aS1, aD1, offs, csr, b1, H1b);

  // layer 2: XP2 = H1 @ W2  (MFMA bf16)
  gemm_mfma<512><<<dim3(256 / 128, (N_NODES + 127) / 128), 256, 0, stream>>>(
      H1b, W2T, XP2b, N_NODES, 256);
  att_logits<1><<<(N_NODES + 3) / 4, 256, 0, stream>>>(XP2b, as2, ad2, aS2, aD2);
  gat_agg<1><<<(N_NODES + 3) / 4, 256, 0, stream>>>(XP2b, aS2, aD2, offs, csr, b2, H2);

  // mean over nodes + fc
  colsum_k<<<200, 256, 0, stream>>>(H2, csum);
  final_k<<<1, 64, 0, stream>>>(csum, fcW, fcb, out);
}

// Round 16
// 366.768 us; speedup vs baseline: 2.3320x; 1.0132x over previous
//
#include <hip/hip_runtime.h>
#include <math.h>

#define N_NODES 50000
#define N_PAD   50048    // padded rows so OOB tile reads stay in-buffer
#define N_EDGES 400000
#define E_TOT   450000   // + self loops
#define IN_DIM  133
#define K1      160      // IN_DIM padded to /32
#define HID     256
#define NEG_SLOPE 0.2f
#define SCAN_BLOCKS 196  // 196*256 = 50176 >= 50000

typedef unsigned int uint;
typedef unsigned short ushort;
typedef __attribute__((ext_vector_type(8))) short short8;
typedef __attribute__((ext_vector_type(4))) float f32x4;

// ---------------- bf16 helpers ----------------
__device__ __forceinline__ float bf_lo(uint u) { return __uint_as_float(u << 16); }
__device__ __forceinline__ float bf_hi(uint u) { return __uint_as_float(u & 0xffff0000u); }
__device__ __forceinline__ uint f2bf1(float f) {  // round-to-nearest-even
  uint u = __float_as_uint(f);
  return (u + 0x7fffu + ((u >> 16) & 1u)) >> 16;
}
__device__ __forceinline__ uint pack_bf2(float lo, float hi) {
  return f2bf1(lo) | (f2bf1(hi) << 16);
}

// ---------------- wave helpers (wave64) ----------------
__device__ __forceinline__ float wave_max(float v) {
#pragma unroll
  for (int m = 1; m < 64; m <<= 1) v = fmaxf(v, __shfl_xor(v, m));
  return v;
}
__device__ __forceinline__ float wave_sum(float v) {
#pragma unroll
  for (int m = 1; m < 64; m <<= 1) v += __shfl_xor(v, m);
  return v;
}

// ---------------- CSR build ----------------
__global__ void zero_k(int* __restrict__ cnt, float* __restrict__ csum) {
  int t = blockIdx.x * 256 + threadIdx.x;
  if (t < N_NODES) cnt[t] = 0;
  if (t < 256) csum[t] = 0.f;
}

__global__ void hist_k(const int* __restrict__ ei, int* __restrict__ cnt) {
  int e = blockIdx.x * 256 + threadIdx.x;
  if (e >= E_TOT) return;
  int dst = (e < N_EDGES) ? ei[N_EDGES + e] : (e - N_EDGES);
  atomicAdd(&cnt[dst], 1);
}

// hierarchical exclusive scan of cnt[50000] -> offs/pos (3 parallel kernels)
__global__ void scan1_k(const int* __restrict__ cnt, int* __restrict__ bsum) {
  __shared__ int sh[256];
  const int t = threadIdx.x, b = blockIdx.x;
  const int idx = b * 256 + t;
  sh[t] = (idx < N_NODES) ? cnt[idx] : 0;
  __syncthreads();
  for (int off = 128; off > 0; off >>= 1) {
    if (t < off) sh[t] += sh[t + off];
    __syncthreads();
  }
  if (t == 0) bsum[b] = sh[0];
}

__global__ void scan2_k(const int* __restrict__ bsum, int* __restrict__ boff) {
  __shared__ int sh[256];
  const int t = threadIdx.x;
  sh[t] = (t < SCAN_BLOCKS) ? bsum[t] : 0;
  __syncthreads();
  for (int off = 1; off < 256; off <<= 1) {
    int v = (t >= off) ? sh[t - off] : 0;
    __syncthreads();
    sh[t] += v;
    __syncthreads();
  }
  if (t < SCAN_BLOCKS) boff[t] = (t > 0) ? sh[t - 1] : 0;  // exclusive
}

__global__ void scan3_k(const int* __restrict__ cnt, const int* __restrict__ boff,
                        int* __restrict__ offs, int* __restrict__ pos) {
  __shared__ int sh[256];
  const int t = threadIdx.x, b = blockIdx.x;
  const int idx = b * 256 + t;
  const int v = (idx < N_NODES) ? cnt[idx] : 0;
  sh[t] = v;
  __syncthreads();
  for (int off = 1; off < 256; off <<= 1) {
    int u = (t >= off) ? sh[t - off] : 0;
    __syncthreads();
    sh[t] += u;
    __syncthreads();
  }
  const int ex = sh[t] - v + boff[b];  // exclusive prefix
  if (idx < N_NODES) { offs[idx] = ex; pos[idx] = ex; }
  if (idx == N_NODES - 1) offs[N_NODES] = ex + v;  // == E_TOT
}

__global__ void scatter_k(const int* __restrict__ ei, int* __restrict__ pos,
                          int* __restrict__ csr_src) {
  int e = blockIdx.x * 256 + threadIdx.x;
  if (e >= E_TOT) return;
  int src, dst;
  if (e < N_EDGES) { src = ei[e]; dst = ei[N_EDGES + e]; }
  else             { src = e - N_EDGES; dst = src; }
  int p = atomicAdd(&pos[dst], 1);
  csr_src[p] = src;
}

// ---------------- fp32 -> bf16 converts / weight transposes ----------------
__global__ void conv_x_k(const float* __restrict__ x, ushort* __restrict__ xb) {
  // xb[N_PAD][K1]; zero pad rows>=N_NODES and cols>=IN_DIM
  int t = blockIdx.x * 256 + threadIdx.x;
  if (t >= N_PAD * (K1 / 2)) return;
  int r = t / (K1 / 2), cc = (t % (K1 / 2)) * 2;
  float v0 = 0.f, v1 = 0.f;
  if (r < N_NODES) {
    if (cc < IN_DIM) v0 = x[(size_t)r * IN_DIM + cc];
    if (cc + 1 < IN_DIM) v1 = x[(size_t)r * IN_DIM + cc + 1];
  }
  *(uint*)&xb[(size_t)r * K1 + cc] = pack_bf2(v0, v1);
}

__global__ void conv_w1t_k(const float* __restrict__ W1, ushort* __restrict__ w1t) {
  // w1t[512][K1] = W1[k][n]^T, zero pad k>=IN_DIM
  int t = blockIdx.x * 256 + threadIdx.x;
  if (t >= 512 * (K1 / 2)) return;
  int n = t / (K1 / 2), cc = (t % (K1 / 2)) * 2;
  float v0 = (cc < IN_DIM) ? W1[(size_t)cc * 512 + n] : 0.f;
  float v1 = (cc + 1 < IN_DIM) ? W1[(size_t)(cc + 1) * 512 + n] : 0.f;
  *(uint*)&w1t[(size_t)n * K1 + cc] = pack_bf2(v0, v1);
}

__global__ void conv_w2t_k(const float* __restrict__ W2, ushort* __restrict__ w2t) {
  // w2t[256][512] = W2[k][n]^T
  int t = blockIdx.x * 256 + threadIdx.x;
  if (t >= 256 * 256) return;
  int n = t / 256, cc = (t % 256) * 2;
  *(uint*)&w2t[(size_t)n * 512 + cc] =
      pack_bf2(W2[(size_t)cc * 256 + n], W2[(size_t)(cc + 1) * 256 + n]);
}

// ---------------- MFMA bf16 GEMM: C[M][N] = A[M][K] * BT[N][K]^T ------------
// 128x128 tile, 4 waves, each wave 64x64 via 4x4 of 16x16x32 frags.
// A/B frag: lane l -> row/col = l&15, k = 8*(l>>4)+j. C/D: col=l&15, row=(l>>4)*4+reg.
__device__ __forceinline__ void gload_lds16(const ushort* g, ushort* l) {
  __builtin_amdgcn_global_load_lds(
      (const __attribute__((address_space(1))) void*)g,
      (__attribute__((address_space(3))) void*)l, 16, 0, 0);
}

template <int KD>
__global__ __launch_bounds__(256) void gemm_mfma(
    const ushort* __restrict__ A,   // [>=M][KD] bf16 (rows padded to tile)
    const ushort* __restrict__ BT,  // [N][KD] bf16
    ushort* __restrict__ C,         // [M][N] bf16
    int M, int N) {
  __shared__ ushort As[128][32];
  __shared__ ushort Bs[128][32];
  const int bm = blockIdx.y * 128;
  const int bn = blockIdx.x * 128;
  const int tid = threadIdx.x;
  const int wv = tid >> 6, lane = tid & 63;
  const int wr = (wv >> 1) * 64;   // wave's row quadrant
  const int wc = (wv & 1) * 64;    // wave's col quadrant
  const int fr = lane & 15;
  const int fg = lane >> 4;
  // staging coords: thread t covers (row = t>>2, chunk = t&3) and row+64
  const int sr = tid >> 2;
  const int sc = (tid & 3) * 8;
  // wave-uniform LDS bases for global_load_lds (lane i lands at base + i*16B)
  ushort* a_lo = &As[wv * 16][0];
  ushort* b_lo = &Bs[wv * 16][0];

  f32x4 acc[4][4] = {};

  for (int k0 = 0; k0 < KD; k0 += 32) {
    gload_lds16(&A[(size_t)(bm + sr) * KD + k0 + sc], a_lo);
    gload_lds16(&A[(size_t)(bm + sr + 64) * KD + k0 + sc], &As[64 + wv * 16][0]);
    gload_lds16(&BT[(size_t)(bn + sr) * KD + k0 + sc], b_lo);
    gload_lds16(&BT[(size_t)(bn + sr + 64) * KD + k0 + sc], &Bs[64 + wv * 16][0]);
    __syncthreads();

    short8 af[4], bfr[4];
#pragma unroll
    for (int mi = 0; mi < 4; ++mi)
      af[mi] = *(const short8*)&As[wr + mi * 16 + fr][fg * 8];
#pragma unroll
    for (int ni = 0; ni < 4; ++ni)
      bfr[ni] = *(const short8*)&Bs[wc + ni * 16 + fr][fg * 8];
#pragma unroll
    for (int mi = 0; mi < 4; ++mi)
#pragma unroll
      for (int ni = 0; ni < 4; ++ni)
        acc[mi][ni] = __builtin_amdgcn_mfma_f32_16x16x32_bf16(
            af[mi], bfr[ni], acc[mi][ni], 0, 0, 0);
    __syncthreads();
  }

#pragma unroll
  for (int mi = 0; mi < 4; ++mi) {
#pragma unroll
    for (int ni = 0; ni < 4; ++ni) {
      const int col = bn + wc + ni * 16 + fr;
      const int row0 = bm + wr + mi * 16 + fg * 4;
#pragma unroll
      for (int t = 0; t < 4; ++t) {
        const int row = row0 + t;
        if (row < M) C[(size_t)row * N + col] = (ushort)f2bf1(acc[mi][ni][t]);
      }
    }
  }
}

// ---------------- per-(node,head) attention logits from bf16 xp ------------
template <int HEADS>
__global__ __launch_bounds__(256) void att_logits(
    const ushort* __restrict__ xpb, const float* __restrict__ att_src,
    const float* __restrict__ att_dst, float* __restrict__ a_s,
    float* __restrict__ a_d) {
  const int wid = (blockIdx.x << 2) + (threadIdx.x >> 6);
  const int lane = threadIdx.x & 63;
  if (wid >= N_NODES * HEADS) return;
  const int head = wid % HEADS;
  const uint2 xv = *(const uint2*)(xpb + (size_t)wid * HID + lane * 4);
  const float x0 = bf_lo(xv.x), x1 = bf_hi(xv.x), x2 = bf_lo(xv.y), x3 = bf_hi(xv.y);
  const float4 sv = *(const float4*)(att_src + head * HID + lane * 4);
  const float4 dv = *(const float4*)(att_dst + head * HID + lane * 4);
  float ps = x0 * sv.x + x1 * sv.y + x2 * sv.z + x3 * sv.w;
  float pd = x0 * dv.x + x1 * dv.y + x2 * dv.z + x3 * dv.w;
  ps = wave_sum(ps);
  pd = wave_sum(pd);
  if (lane == 0) { a_s[wid] = ps; a_d[wid] = pd; }
}

// ---------- fused segment softmax + bf16 gather-aggregate + bias + ELU -----
// HEADS==2: out is bf16 [node][512] (feeds MFMA gemm2). HEADS==1: fp32 [node][256].
// Accumulate loop unrolled x4 with batched gathers (4 loads in flight per wave):
// VGPR=20 profile showed the rolled loop kept only 1 gather outstanding (MLP-bound).
template <int HEADS>
__global__ __launch_bounds__(256) void gat_agg(
    const ushort* __restrict__ xpb, const float* __restrict__ a_s,
    const float* __restrict__ a_d, const int* __restrict__ offs,
    const int* __restrict__ csr, const float* __restrict__ bias,
    void* __restrict__ outv) {
  const int node = (blockIdx.x << 2) + (threadIdx.x >> 6);
  const int lane = threadIdx.x & 63;
  if (node >= N_NODES) return;
  const int beg = offs[node], end = offs[node + 1];
  const int deg = end - beg;
  const float ad0 = a_d[node * HEADS + 0];
  const float ad1 = (HEADS == 2) ? a_d[node * HEADS + 1] : 0.f;

  if (deg <= 64) {
    int s = 0;
    float e0 = -INFINITY, e1 = -INFINITY;
    if (lane < deg) {
      s = csr[beg + lane];
      float v0 = a_s[s * HEADS + 0] + ad0;
      e0 = v0 > 0.f ? v0 : NEG_SLOPE * v0;
      if (HEADS == 2) {
        float v1 = a_s[s * HEADS + 1] + ad1;
        e1 = v1 > 0.f ? v1 : NEG_SLOPE * v1;
      }
    }
    const float m0 = wave_max(e0);
    const float p0 = (lane < deg) ? __expf(e0 - m0) : 0.f;
    const float z0 = wave_sum(p0);
    const float al0 = p0 / (z0 + 1e-16f);
    float al1 = 0.f;
    if (HEADS == 2) {
      const float m1 = wave_max(e1);
      const float p1 = (lane < deg) ? __expf(e1 - m1) : 0.f;
      const float z1 = wave_sum(p1);
      al1 = p1 / (z1 + 1e-16f);
    }

    if (HEADS == 2) {
      float acc[8] = {};
      int i = 0;
      for (; i + 4 <= deg; i += 4) {
        int sj[4];
        float aaj[4];
        uint4 vj[4];
#pragma unroll
        for (int j = 0; j < 4; ++j) {
          sj[j] = __shfl(s, i + j);
          float a0 = __shfl(al0, i + j);
          float a1 = __shfl(al1, i + j);
          aaj[j] = (lane < 32) ? a0 : a1;
        }
#pragma unroll
        for (int j = 0; j < 4; ++j)
          vj[j] = *(const uint4*)(xpb + (size_t)sj[j] * 512 + lane * 8);
#pragma unroll
        for (int j = 0; j < 4; ++j) {
          acc[0] = fmaf(aaj[j], bf_lo(vj[j].x), acc[0]);
          acc[1] = fmaf(aaj[j], bf_hi(vj[j].x), acc[1]);
          acc[2] = fmaf(aaj[j], bf_lo(vj[j].y), acc[2]);
          acc[3] = fmaf(aaj[j], bf_hi(vj[j].y), acc[3]);
          acc[4] = fmaf(aaj[j], bf_lo(vj[j].z), acc[4]);
          acc[5] = fmaf(aaj[j], bf_hi(vj[j].z), acc[5]);
          acc[6] = fmaf(aaj[j], bf_lo(vj[j].w), acc[6]);
          acc[7] = fmaf(aaj[j], bf_hi(vj[j].w), acc[7]);
        }
      }
      for (; i < deg; ++i) {
        int si = __shfl(s, i);
        float a0 = __shfl(al0, i);
        float a1 = __shfl(al1, i);
        float aa = (lane < 32) ? a0 : a1;
        uint4 v = *(const uint4*)(xpb + (size_t)si * 512 + lane * 8);
        acc[0] = fmaf(aa, bf_lo(v.x), acc[0]);
        acc[1] = fmaf(aa, bf_hi(v.x), acc[1]);
        acc[2] = fmaf(aa, bf_lo(v.y), acc[2]);
        acc[3] = fmaf(aa, bf_hi(v.y), acc[3]);
        acc[4] = fmaf(aa, bf_lo(v.z), acc[4]);
        acc[5] = fmaf(aa, bf_hi(v.z), acc[5]);
        acc[6] = fmaf(aa, bf_lo(v.w), acc[6]);
        acc[7] = fmaf(aa, bf_hi(v.w), acc[7]);
      }
      const int col = lane * 8;
      const float4 b0 = *(const float4*)(bias + col);
      const float4 b1 = *(const float4*)(bias + col + 4);
      float o[8];
      o[0] = acc[0] + b0.x; o[1] = acc[1] + b0.y; o[2] = acc[2] + b0.z; o[3] = acc[3] + b0.w;
      o[4] = acc[4] + b1.x; o[5] = acc[5] + b1.y; o[6] = acc[6] + b1.z; o[7] = acc[7] + b1.w;
#pragma unroll
      for (int j = 0; j < 8; ++j) o[j] = o[j] > 0.f ? o[j] : __expf(o[j]) - 1.f;
      uint4 w;
      w.x = pack_bf2(o[0], o[1]); w.y = pack_bf2(o[2], o[3]);
      w.z = pack_bf2(o[4], o[5]); w.w = pack_bf2(o[6], o[7]);
      *(uint4*)((ushort*)outv + (size_t)node * 512 + col) = w;
    } else {
      float acc[4] = {};
      int i = 0;
      for (; i + 4 <= deg; i += 4) {
        int sj[4];
        float aaj[4];
        uint2 vj[4];
#pragma unroll
        for (int j = 0; j < 4; ++j) {
          sj[j] = __shfl(s, i + j);
          aaj[j] = __shfl(al0, i + j);
        }
#pragma unroll
        for (int j = 0; j < 4; ++j)
          vj[j] = *(const uint2*)(xpb + (size_t)sj[j] * 256 + lane * 4);
#pragma unroll
        for (int j = 0; j < 4; ++j) {
          acc[0] = fmaf(aaj[j], bf_lo(vj[j].x), acc[0]);
          acc[1] = fmaf(aaj[j], bf_hi(vj[j].x), acc[1]);
          acc[2] = fmaf(aaj[j], bf_lo(vj[j].y), acc[2]);
          acc[3] = fmaf(aaj[j], bf_hi(vj[j].y), acc[3]);
        }
      }
      for (; i < deg; ++i) {
        int si = __shfl(s, i);
        float aa = __shfl(al0, i);
        uint2 v = *(const uint2*)(xpb + (size_t)si * 256 + lane * 4);
        acc[0] = fmaf(aa, bf_lo(v.x), acc[0]);
        acc[1] = fmaf(aa, bf_hi(v.x), acc[1]);
        acc[2] = fmaf(aa, bf_lo(v.y), acc[2]);
        acc[3] = fmaf(aa, bf_hi(v.y), acc[3]);
      }
      const int col = lane * 4;
      const float4 bb = *(const float4*)(bias + col);
      float o0 = acc[0] + bb.x, o1 = acc[1] + bb.y, o2 = acc[2] + bb.z, o3 = acc[3] + bb.w;
      o0 = o0 > 0.f ? o0 : __expf(o0) - 1.f;
      o1 = o1 > 0.f ? o1 : __expf(o1) - 1.f;
      o2 = o2 > 0.f ? o2 : __expf(o2) - 1.f;
      o3 = o3 > 0.f ? o3 : __expf(o3) - 1.f;
      *(float4*)((float*)outv + (size_t)node * 256 + col) = make_float4(o0, o1, o2, o3);
    }
  } else {
    // rare fallback (deg > 64): 3-pass per head
    for (int h = 0; h < HEADS; ++h) {
      const float adh = (h == 0) ? ad0 : ad1;
      float m = -INFINITY;
      for (int i = beg + lane; i < end; i += 64) {
        int s2 = csr[i];
        float e = a_s[s2 * HEADS + h] + adh;
        e = e > 0.f ? e : NEG_SLOPE * e;
        m = fmaxf(m, e);
      }
      m = wave_max(m);
      float z = 0.f;
      for (int i = beg + lane; i < end; i += 64) {
        int s2 = csr[i];
        float e = a_s[s2 * HEADS + h] + adh;
        e = e > 0.f ? e : NEG_SLOPE * e;
        z += __expf(e - m);
      }
      z = wave_sum(z) + 1e-16f;
      const float invz = 1.f / z;
      float acc[4] = {};
      for (int i = beg; i < end; ++i) {
        int s2 = csr[i];
        float e = a_s[s2 * HEADS + h] + adh;
        e = e > 0.f ? e : NEG_SLOPE * e;
        float al = __expf(e - m) * invz;
        uint2 v = *(const uint2*)(xpb + ((size_t)s2 * HEADS + h) * HID + lane * 4);
        acc[0] = fmaf(al, bf_lo(v.x), acc[0]);
        acc[1] = fmaf(al, bf_hi(v.x), acc[1]);
        acc[2] = fmaf(al, bf_lo(v.y), acc[2]);
        acc[3] = fmaf(al, bf_hi(v.y), acc[3]);
      }
      const int oc = h * HID + lane * 4;
      const float4 bb = *(const float4*)(bias + oc);
      float o0 = acc[0] + bb.x, o1 = acc[1] + bb.y, o2 = acc[2] + bb.z, o3 = acc[3] + bb.w;
      o0 = o0 > 0.f ? o0 : __expf(o0) - 1.f;
      o1 = o1 > 0.f ? o1 : __expf(o1) - 1.f;
      o2 = o2 > 0.f ? o2 : __expf(o2) - 1.f;
      o3 = o3 > 0.f ? o3 : __expf(o3) - 1.f;
      if (HEADS == 2) {
        uint2 w = make_uint2(pack_bf2(o0, o1), pack_bf2(o2, o3));
        *(uint2*)((ushort*)outv + (size_t)node * 512 + oc) = w;
      } else {
        *(float4*)((float*)outv + (size_t)node * 256 + oc) = make_float4(o0, o1, o2, o3);
      }
    }
  }
}

// ---------------- mean over nodes + fc head ----------------
__global__ void colsum_k(const float* __restrict__ h2, float* __restrict__ sum) {
  const int c = threadIdx.x;
  const int r0 = blockIdx.x * 250;
  float s = 0.f;
  for (int r = r0; r < r0 + 250; ++r) s += h2[(size_t)r * HID + c];
  atomicAdd(&sum[c], s);
}

__global__ void final_k(const float* __restrict__ csum, const float* __restrict__ fcW,
                        const float* __restrict__ fcb, float* __restrict__ out) {
  const int lane = threadIdx.x;
  float p0 = 0.f, p1 = 0.f, p2 = 0.f;
  for (int c = lane; c < HID; c += 64) {
    float v = csum[c] * (1.f / (float)N_NODES);
    p0 = fmaf(v, fcW[c * 3 + 0], p0);
    p1 = fmaf(v, fcW[c * 3 + 1], p1);
    p2 = fmaf(v, fcW[c * 3 + 2], p2);
  }
  p0 = wave_sum(p0); p1 = wave_sum(p1); p2 = wave_sum(p2);
  if (lane == 0) {
    out[0] = p0 + fcb[0];
    out[1] = p1 + fcb[1];
    out[2] = p2 + fcb[2];
  }
}

// ---------------- launch ----------------
extern "C" void kernel_launch(void* const* d_in, const int* in_sizes, int n_in,
                              void* d_out, int out_size, void* d_ws, size_t ws_size,
                              hipStream_t stream) {
  const float* x   = (const float*)d_in[0];
  const int*   ei  = (const int*)d_in[1];
  const float* W1  = (const float*)d_in[2];
  const float* as1 = (const float*)d_in[3];
  const float* ad1 = (const float*)d_in[4];
  const float* b1  = (const float*)d_in[5];
  const float* W2  = (const float*)d_in[6];
  const float* as2 = (const float*)d_in[7];
  const float* ad2 = (const float*)d_in[8];
  const float* b2  = (const float*)d_in[9];
  const float* fcW = (const float*)d_in[10];
  const float* fcb = (const float*)d_in[11];
  float* out = (float*)d_out;

  char* w = (char*)d_ws;
  size_t o = 0;
  auto alloc = [&](size_t bytes) {
    void* p = w + o;
    o = (o + bytes + 255) & ~(size_t)255;
    return p;
  };
  ushort* XB   = (ushort*)alloc((size_t)N_PAD * K1 * 2);    // x bf16, padded
  ushort* W1T  = (ushort*)alloc((size_t)512 * K1 * 2);      // W1^T bf16
  ushort* W2T  = (ushort*)alloc((size_t)256 * 512 * 2);     // W2^T bf16
  ushort* XPb  = (ushort*)alloc((size_t)N_NODES * 512 * 2); // xp1 bf16
  ushort* H1b  = (ushort*)alloc((size_t)N_PAD * 512 * 2);   // h1 bf16 (gemm2 A)
  ushort* XP2b = (ushort*)alloc((size_t)N_NODES * 256 * 2); // xp2 bf16
  float*  H2   = (float*)alloc((size_t)N_NODES * 256 * 4);  // h2 fp32
  float* aS1 = (float*)alloc((size_t)N_NODES * 2 * 4);
  float* aD1 = (float*)alloc((size_t)N_NODES * 2 * 4);
  float* aS2 = (float*)alloc((size_t)N_NODES * 4);
  float* aD2 = (float*)alloc((size_t)N_NODES * 4);
  int* cnt   = (int*)alloc((size_t)N_NODES * 4);
  int* offs  = (int*)alloc((size_t)(N_NODES + 1) * 4);
  int* pos   = (int*)alloc((size_t)(N_NODES + 1) * 4);
  int* csr   = (int*)alloc((size_t)E_TOT * 4);
  int* bsum  = (int*)alloc((size_t)SCAN_BLOCKS * 4);
  int* boff  = (int*)alloc((size_t)SCAN_BLOCKS * 4);
  float* csum = (float*)alloc(256 * 4);

  // CSR build + input converts
  zero_k<<<(N_NODES + 255) / 256, 256, 0, stream>>>(cnt, csum);
  hist_k<<<(E_TOT + 255) / 256, 256, 0, stream>>>(ei, cnt);
  scan1_k<<<SCAN_BLOCKS, 256, 0, stream>>>(cnt, bsum);
  scan2_k<<<1, 256, 0, stream>>>(bsum, boff);
  scan3_k<<<SCAN_BLOCKS, 256, 0, stream>>>(cnt, boff, offs, pos);
  scatter_k<<<(E_TOT + 255) / 256, 256, 0, stream>>>(ei, pos, csr);
  conv_x_k<<<(N_PAD * (K1 / 2) + 255) / 256, 256, 0, stream>>>(x, XB);
  conv_w1t_k<<<(512 * (K1 / 2) + 255) / 256, 256, 0, stream>>>(W1, W1T);
  conv_w2t_k<<<(256 * 256 + 255) / 256, 256, 0, stream>>>(W2, W2T);

  // layer 1: XP1 = XB @ W1  (MFMA bf16)
  gemm_mfma<K1><<<dim3(512 / 128, (N_NODES + 127) / 128), 256, 0, stream>>>(
      XB, W1T, XPb, N_NODES, 512);
  att_logits<2><<<(N_NODES * 2 + 3) / 4, 256, 0, stream>>>(XPb, as1, ad1, aS1, aD1);
  gat_agg<2><<<(N_NODES + 3) / 4, 256, 0, stream>>>(XPb, aS1, aD1, offs, csr, b1, H1b);

  // layer 2: XP2 = H1 @ W2  (MFMA bf16)
  gemm_mfma<512><<<dim3(256 / 128, (N_NODES + 127) / 128), 256, 0, stream>>>(
      H1b, W2T, XP2b, N_NODES, 256);
  att_logits<1><<<(N_NODES + 3) / 4, 256, 0, stream>>>(XP2b, as2, ad2, aS2, aD2);
  gat_agg<1><<<(N_NODES + 3) / 4, 256, 0, stream>>>(XP2b, aS2, aD2, offs, csr, b2, H2);

  // mean over nodes + fc
  colsum_k<<<200, 256, 0, stream>>>(H2, csum);
  final_k<<<1, 64, 0, stream>>>(csum, fcW, fcb, out);
}